// Round 3
// baseline (464.876 us; speedup 1.0000x reference)
//
#include <hip/hip_runtime.h>
#include <cstdint>

#define N_NODES 20000
#define N_EDGES 320000
#define ALPHA 0.2f
#define GAT_EPS 1e-16f
#define MPAD 20096           // 157 * 128
#define RBLK 157
#define RHI 20               // ceil(157/8)
#define SCAN_BLKS 80
#define BT_ROWS 1152         // 9 col-blocks * 128

typedef __attribute__((ext_vector_type(8))) _Float16 half8;
typedef __attribute__((ext_vector_type(4))) _Float16 half4t;
typedef __attribute__((ext_vector_type(16))) float f32x16;
typedef __attribute__((ext_vector_type(2))) float f32x2;

__device__ __forceinline__ float elu1(float x) { return x > 0.f ? x : __expf(x) - 1.f; }

__device__ __forceinline__ unsigned char f2fp8(float x) {
    return (unsigned char)(__builtin_amdgcn_cvt_pk_fp8_f32(x, 0.f, 0, false) & 0xff);
}

__device__ __forceinline__ void async16(const void* g, void* l) {
    __builtin_amdgcn_global_load_lds(
        (const __attribute__((address_space(1))) unsigned int*)g,
        (__attribute__((address_space(3))) unsigned int*)l, 16, 0, 0);
}

// packed fp32 fma: d = a*b + c per component (VOP3P, full rate on CDNA)
__device__ __forceinline__ f32x2 pkfma(f32x2 a, f32x2 b, f32x2 c) {
    f32x2 d;
    asm("v_pk_fma_f32 %0, %1, %2, %3" : "=v"(d) : "v"(a), "v"(b), "v"(c));
    return d;
}

template <bool HI>
__device__ __forceinline__ f32x2 cvt8(unsigned int u) {
    return __builtin_amdgcn_cvt_pk_f32_fp8((int)u, HI);
}

// ---------------- CSR build ----------------
__global__ void hist_kernel(const int* __restrict__ dst, int* __restrict__ counts, int E) {
    int e = blockIdx.x * blockDim.x + threadIdx.x;
    if (e < E) atomicAdd(&counts[dst[e]], 1);
}

__global__ void scan1_kernel(const int* __restrict__ counts, int* __restrict__ excl,
                             int* __restrict__ partial, int N) {
    __shared__ int sh[256];
    int t = threadIdx.x, b = blockIdx.x;
    int i = b * 256 + t;
    int v = (i < N) ? counts[i] : 0;
    sh[t] = v;
    __syncthreads();
    for (int d = 1; d < 256; d <<= 1) {
        int x = (t >= d) ? sh[t - d] : 0;
        __syncthreads();
        sh[t] += x;
        __syncthreads();
    }
    if (i < N) excl[i] = sh[t] - v;
    if (t == 255) partial[b] = sh[255];
}

__global__ void scan2_kernel(int* __restrict__ partial) {
    __shared__ int sh[128];
    int t = threadIdx.x;
    int v = (t < SCAN_BLKS) ? partial[t] : 0;
    sh[t] = v;
    __syncthreads();
    for (int d = 1; d < 128; d <<= 1) {
        int x = (t >= d) ? sh[t - d] : 0;
        __syncthreads();
        sh[t] += x;
        __syncthreads();
    }
    if (t < SCAN_BLKS) partial[t] = sh[t] - v;
}

__global__ void scan3_kernel(const int* __restrict__ excl, const int* __restrict__ partial,
                             int* __restrict__ rowptr, int* __restrict__ cursor, int N, int E) {
    int t = threadIdx.x, b = blockIdx.x;
    int i = b * 256 + t;
    if (i < N) {
        int v = excl[i] + partial[b];
        rowptr[i] = v;
        cursor[i] = v;
    }
    if (i == 0) rowptr[N] = E;
}

__global__ void scatter_kernel(const int* __restrict__ src, const int* __restrict__ dst,
                               int* __restrict__ cursor, int* __restrict__ esrc, int E) {
    int e = blockIdx.x * blockDim.x + threadIdx.x;
    if (e < E) {
        int p = atomicAdd(&cursor[dst[e]], 1);
        esrc[p] = src[e];
    }
}

// ---------------- packs ----------------
__global__ void pack_x16(const float* __restrict__ x, _Float16* __restrict__ A) {
    int idx = blockIdx.x * 256 + threadIdx.x;   // MPAD*64
    int r = idx >> 6, c = idx & 63;
    float v = (r < N_NODES && c < 50) ? x[r * 50 + c] : 0.f;
    A[idx] = (_Float16)v;
}

__global__ void pack_bt1(const float* __restrict__ W, _Float16* __restrict__ Bt) {
    int idx = blockIdx.x * 256 + threadIdx.x;   // 1024*64
    int c = idx >> 6, k = idx & 63;
    int h = c >> 8, f = c & 255;
    float v = (k < 50) ? W[((size_t)h * 50 + k) * 256 + f] : 0.f;
    Bt[idx] = (_Float16)v;
}

// generic: BT row c -> head h=c/Fpad, col f=c%Fpad; zero for f>=F (alignment pad)
__global__ void pack_bt16(const float* __restrict__ W, _Float16* __restrict__ Bt,
                          int F, int Fpad, int Ctot) {
    int c = blockIdx.y;
    int k = blockIdx.x * blockDim.x + threadIdx.x;
    float v = 0.f;
    if (c < Ctot) {
        int h = c / Fpad, f = c - h * Fpad;
        if (f < F) v = W[(size_t)h * 1024 * F + (size_t)k * F + f];
    }
    Bt[(size_t)c * 1024 + k] = (_Float16)v;
}

// W~ cols: mode 0 -> appended at BT rows [Nfeat, Nfeat+2H).
// mode 1 (layer 3, Fpad=128): score j goes into pad slot: row = h*128 + 121 + (j>=H).
__global__ __launch_bounds__(64) void wtilde_kernel(const float* __restrict__ W,
                                                    const float* __restrict__ a,
                                                    _Float16* __restrict__ BT, int Kreal,
                                                    int Kdim, int F, int H, int Nfeat,
                                                    int padmode) {
    int k = blockIdx.x, j = blockIdx.y;
    if (j >= 2 * H) return;
    int lane = threadIdx.x;
    int h = j < H ? j : j - H;
    int ao = j < H ? 0 : F;
    float s = 0.f;
    if (k < Kreal) {
        const float* wp = W + ((size_t)h * Kreal + k) * F;
        const float* ap = a + (size_t)h * 2 * F + ao;
        for (int f = lane; f < F; f += 64) s += wp[f] * ap[f];
    }
#pragma unroll
    for (int off = 32; off; off >>= 1) s += __shfl_down(s, off);
    if (lane == 0) {
        int row = padmode ? (h * 128 + 121 + (j >= H ? 1 : 0)) : (Nfeat + j);
        BT[(size_t)row * Kdim + k] = (_Float16)s;
    }
}

// ---------------- fp16 MFMA GEMM (32x32x16) -> fp8 Wh + fp32 score cols ----------------
// 2-phase pipelined (double-buffered LDS, next-tile global_load_lds issued before MFMA).
// l3pad: scores live in head-pad columns (gc%128 in {121,122}) instead of appended cols.
__global__ __launch_bounds__(256) void gemm_f16(const _Float16* __restrict__ A,
                                                const _Float16* __restrict__ BT,
                                                unsigned char* __restrict__ C8,
                                                float* __restrict__ SPRE,
                                                int M, int Nfeat, int ld, int Kdim, int Cblk,
                                                int l3pad) {
    int id = blockIdx.x;
    int xm = id & 7, q = id >> 3;
    int cb = q % Cblk, rh = q / Cblk;
    int rb = rh * 8 + xm;
    if (rb >= RBLK) return;
    __shared__ __align__(16) _Float16 sA[2][128 * 64];
    __shared__ __align__(16) _Float16 sB[2][128 * 64];
    int t = threadIdx.x;
    int row0 = rb * 128, col0 = cb * 128;
    int lane = t & 63, wave = t >> 6;
    int wm = wave >> 1, wn = wave & 1;
    int l31 = lane & 31;
    int lhi = lane >> 5;

    const _Float16* gA = A + (size_t)row0 * Kdim;
    const _Float16* gB = BT + (size_t)col0 * Kdim;

    int sR[4], sgl[4];
#pragma unroll
    for (int i = 0; i < 4; i++) {
        int m = i * 256 + t;
        sR[i] = m >> 3;
        sgl[i] = (m & 7) ^ (sR[i] & 7);
    }

    f32x16 acc[2][2] = {};

    // prologue: stage K-tile 0 into buffer 0
#pragma unroll
    for (int i = 0; i < 4; i++) {
        const _Float16* pa = gA + (size_t)sR[i] * Kdim + sgl[i] * 8;
        const _Float16* pb = gB + (size_t)sR[i] * Kdim + sgl[i] * 8;
        async16(pa, &sA[0][(i * 256 + t) * 8]);
        async16(pb, &sB[0][(i * 256 + t) * 8]);
    }

    int cur = 0;
    for (int k0 = 0; k0 < Kdim; k0 += 64) {
        __syncthreads();           // drains vmcnt: buf[cur] staged; prev buf's ds_reads done
        int nxt = k0 + 64;
        if (nxt < Kdim) {
            int nb = cur ^ 1;      // issue next tile's loads BEFORE compute
#pragma unroll
            for (int i = 0; i < 4; i++) {
                const _Float16* pa = gA + (size_t)sR[i] * Kdim + nxt + sgl[i] * 8;
                const _Float16* pb = gB + (size_t)sR[i] * Kdim + nxt + sgl[i] * 8;
                async16(pa, &sA[nb][(i * 256 + t) * 8]);
                async16(pb, &sB[nb][(i * 256 + t) * 8]);
            }
        }
        const _Float16* cA = sA[cur];
        const _Float16* cB = sB[cur];
#pragma unroll
        for (int kk = 0; kk < 4; kk++) {
            int g = kk * 2 + lhi;
            half8 af[2], bf[2];
#pragma unroll
            for (int mt = 0; mt < 2; mt++) {
                int R = wm * 64 + mt * 32 + l31;
                int gp = g ^ (R & 7);
                af[mt] = *(const half8*)(cA + R * 64 + gp * 8);
            }
#pragma unroll
            for (int nt = 0; nt < 2; nt++) {
                int R = wn * 64 + nt * 32 + l31;
                int gp = g ^ (R & 7);
                bf[nt] = *(const half8*)(cB + R * 64 + gp * 8);
            }
#pragma unroll
            for (int mt = 0; mt < 2; mt++)
#pragma unroll
                for (int nt = 0; nt < 2; nt++)
                    acc[mt][nt] = __builtin_amdgcn_mfma_f32_32x32x16_f16(af[mt], bf[nt], acc[mt][nt], 0, 0, 0);
        }
        cur ^= 1;
    }

    int cb32 = col0 + wn * 64 + l31;
    int rb32 = row0 + wm * 64 + 4 * lhi;
#pragma unroll
    for (int mt = 0; mt < 2; mt++)
#pragma unroll
        for (int nt = 0; nt < 2; nt++) {
            int gc = cb32 + nt * 32;
            if (gc < Nfeat) {
                int fr = gc & 127;
                int sj = (fr - 121) * 6 + (gc >> 7);   // valid only when l3pad && fr in {121,122}
                bool sp = l3pad && (fr == 121 || fr == 122);
#pragma unroll
                for (int r = 0; r < 16; r++) {
                    int gr = rb32 + mt * 32 + (r & 3) + 8 * (r >> 2);
                    if (gr < M) {
                        C8[(size_t)gr * ld + gc] = f2fp8(acc[mt][nt][r]);
                        if (sp) SPRE[(size_t)sj * N_NODES + gr] = acc[mt][nt][r];
                    }
                }
            } else if (!l3pad && gc < Nfeat + 12) {
                int j = gc - Nfeat;
#pragma unroll
                for (int r = 0; r < 16; r++) {
                    int gr = rb32 + mt * 32 + (r & 3) + 8 * (r >> 2);
                    if (gr < M) SPRE[(size_t)j * N_NODES + gr] = acc[mt][nt][r];
                }
            }
        }
}

// ---------------- fused attention + aggregation, Fout=256 layers ----------------
// block = node, 4 waves. Phase 1: wave h = head h online softmax (m,s).
// Phase 2 per 64-edge chunk: each wave writes its head's p to LDS, then edges are
// split j%4 across waves; ONE wave gathers the WHOLE 1024B row (64 lanes x dwordx4)
// and accumulates 16 features/lane via cvt_pk_f32_fp8 + v_pk_fma_f32.
// Cross-wave partials reduced through LDS at the end.
__global__ __launch_bounds__(256) void attagg256_kernel(const int* __restrict__ rowptr,
                                                        const int* __restrict__ esrc,
                                                        const float* __restrict__ SPRE,
                                                        const unsigned char* __restrict__ WH8,
                                                        _Float16* __restrict__ X16,
                                                        int use_skip, int N) {
    __shared__ float part[4 * 1024];
    __shared__ float Pp[4][72];
    __shared__ int Ii[64];
    int n = blockIdx.x;
    int t = threadIdx.x;
    int wv = t >> 6;
    int lane = t & 63;
    int start = rowptr[n], end = rowptr[n + 1];
    const float* ss = SPRE + (size_t)wv * N;
    float sd = SPRE[(size_t)(4 + wv) * N + n];

    // ---- phase 1: online softmax (m, s) per head(wave) ----
    float m = -1e30f, s = 0.f;
    int sidx = 0; float ssc = -1e30f;   // last chunk's per-lane (idx, score)
    for (int e0 = start; e0 < end; e0 += 64) {
        int e = e0 + lane;
        bool act = e < end;
        int idx = act ? esrc[e] : 0;
        float sc = -1e30f;
        if (act) {
            sc = ss[idx] + sd;
            sc = sc > 0.f ? sc : ALPHA * sc;
        }
        sidx = idx; ssc = sc;
        float mn = fmaxf(m, sc);
        s = s * __expf(m - mn) + (act ? __expf(sc - mn) : 0.f);
        m = mn;
    }
#pragma unroll
    for (int off = 1; off < 64; off <<= 1) {
        float mo = __shfl_xor(m, off);
        float so = __shfl_xor(s, off);
        float mn = fmaxf(m, mo);
        s = s * __expf(m - mn) + so * __expf(mo - mn);
        m = mn;
    }
    float inv = 1.f / (s + GAT_EPS);

    // ---- phase 2 ----
    int hf = lane >> 4;                       // feature-head of this lane's 16B slot
    const unsigned char* Wb = WH8 + lane * 16;
    f32x2 acc[8] = {};
    int lastStart = start + (((end - start - 1) >> 6) << 6);
    for (int e0 = start; e0 < end; e0 += 64) {
        int e = e0 + lane;
        bool act = e < end;
        int idx; float sc;
        if (e0 == lastStart) { idx = sidx; sc = ssc; }
        else {
            idx = act ? esrc[e] : 0;
            sc = -1e30f;
            if (act) {
                sc = ss[idx] + sd;
                sc = sc > 0.f ? sc : ALPHA * sc;
            }
        }
        float p = act ? __expf(sc - m) * inv : 0.f;
        __syncthreads();                      // prev chunk's LDS reads done
        Pp[wv][lane] = p;
        if (wv == 0) Ii[lane] = idx;
        __syncthreads();
        int cnt = end - e0; if (cnt > 64) cnt = 64;
        int j = wv;
        if (j < cnt) {
            int ij = Ii[j];
            float pj = Pp[hf][j];
            uint4 w = *(const uint4*)(Wb + ((size_t)(unsigned)ij << 10));
            for (;;) {
                int j2 = j + 4;
                bool more = j2 < cnt;
                int ij2 = 0; float pj2 = 0.f; uint4 w2;
                if (more) {
                    ij2 = Ii[j2];
                    pj2 = Pp[hf][j2];
                    w2 = *(const uint4*)(Wb + ((size_t)(unsigned)ij2 << 10));
                }
                f32x2 pv; pv.x = pj; pv.y = pj;
                acc[0] = pkfma(cvt8<false>(w.x), pv, acc[0]);
                acc[1] = pkfma(cvt8<true>(w.x),  pv, acc[1]);
                acc[2] = pkfma(cvt8<false>(w.y), pv, acc[2]);
                acc[3] = pkfma(cvt8<true>(w.y),  pv, acc[3]);
                acc[4] = pkfma(cvt8<false>(w.z), pv, acc[4]);
                acc[5] = pkfma(cvt8<true>(w.z),  pv, acc[5]);
                acc[6] = pkfma(cvt8<false>(w.w), pv, acc[6]);
                acc[7] = pkfma(cvt8<true>(w.w),  pv, acc[7]);
                if (!more) break;
                j = j2; pj = pj2; w = w2;
            }
        }
    }

    // ---- cross-wave reduction + epilogue ----
#pragma unroll
    for (int k = 0; k < 8; k++)
        *(f32x2*)&part[wv * 1024 + lane * 16 + 2 * k] = acc[k];
    __syncthreads();
    int f0 = t * 4;
    float4 q0 = *(const float4*)&part[f0];
    float4 q1 = *(const float4*)&part[1024 + f0];
    float4 q2 = *(const float4*)&part[2048 + f0];
    float4 q3 = *(const float4*)&part[3072 + f0];
    float a0 = q0.x + q1.x + q2.x + q3.x;
    float a1 = q0.y + q1.y + q2.y + q3.y;
    float a2 = q0.z + q1.z + q2.z + q3.z;
    float a3 = q0.w + q1.w + q2.w + q3.w;
    size_t o = (size_t)n * 1024 + f0;
    float v0, v1, v2, v3;
    if (use_skip) {
        half4t sk = *(const half4t*)(X16 + o);
        v0 = elu1(elu1(a0) + (float)sk.x);
        v1 = elu1(elu1(a1) + (float)sk.y);
        v2 = elu1(elu1(a2) + (float)sk.z);
        v3 = elu1(elu1(a3) + (float)sk.w);
    } else {
        v0 = elu1(elu1(a0)); v1 = elu1(elu1(a1));
        v2 = elu1(elu1(a2)); v3 = elu1(elu1(a3));
    }
    half4t r;
    r.x = (_Float16)v0; r.y = (_Float16)v1; r.z = (_Float16)v2; r.w = (_Float16)v3;
    *(half4t*)(X16 + o) = r;
}

// ---------------- fused attention + aggregation, layer 3 (6 heads @128B stride) --------
// block = node, 6 waves. Wh3 row = 6*128 = 768 B; lanes 0..47 x dwordx4 cover the row.
// Pad cols 123..127 are exact zeros; cols 121/122 hold fp8'd scores (garbage here) --
// both discarded since only f<121 is emitted. Cross-wave + cross-head reduce in LDS.
__global__ __launch_bounds__(384) void attagg726_kernel(const int* __restrict__ rowptr,
                                                        const int* __restrict__ esrc,
                                                        const float* __restrict__ SPRE,
                                                        const unsigned char* __restrict__ WH8,
                                                        float* __restrict__ out, int N) {
    __shared__ float part[6 * 768];
    __shared__ float Pp[6][72];
    __shared__ int Ii[64];
    int n = blockIdx.x;
    int t = threadIdx.x;
    int wv = t >> 6;
    int lane = t & 63;
    int start = rowptr[n], end = rowptr[n + 1];
    const float* ss = SPRE + (size_t)wv * N;
    float sd = SPRE[(size_t)(6 + wv) * N + n];

    float m = -1e30f, s = 0.f;
    int sidx = 0; float ssc = -1e30f;
    for (int e0 = start; e0 < end; e0 += 64) {
        int e = e0 + lane;
        bool act = e < end;
        int idx = act ? esrc[e] : 0;
        float sc = -1e30f;
        if (act) {
            sc = ss[idx] + sd;
            sc = sc > 0.f ? sc : ALPHA * sc;
        }
        sidx = idx; ssc = sc;
        float mn = fmaxf(m, sc);
        s = s * __expf(m - mn) + (act ? __expf(sc - mn) : 0.f);
        m = mn;
    }
#pragma unroll
    for (int off = 1; off < 64; off <<= 1) {
        float mo = __shfl_xor(m, off);
        float so = __shfl_xor(s, off);
        float mn = fmaxf(m, mo);
        s = s * __expf(m - mn) + so * __expf(mo - mn);
        m = mn;
    }
    float inv = 1.f / (s + GAT_EPS);

    int hf = (lane < 48) ? (lane >> 3) : 0;   // feature-head; clamp idle lanes
    const unsigned char* Wb = WH8 + lane * 16;
    f32x2 acc[8] = {};
    int lastStart = start + (((end - start - 1) >> 6) << 6);
    for (int e0 = start; e0 < end; e0 += 64) {
        int e = e0 + lane;
        bool act = e < end;
        int idx; float sc;
        if (e0 == lastStart) { idx = sidx; sc = ssc; }
        else {
            idx = act ? esrc[e] : 0;
            sc = -1e30f;
            if (act) {
                sc = ss[idx] + sd;
                sc = sc > 0.f ? sc : ALPHA * sc;
            }
        }
        float p = act ? __expf(sc - m) * inv : 0.f;
        __syncthreads();
        Pp[wv][lane] = p;
        if (wv == 0) Ii[lane] = idx;
        __syncthreads();
        int cnt = end - e0; if (cnt > 64) cnt = 64;
        int j = wv;
        if (j < cnt) {
            int ij = Ii[j];
            float pj = Pp[hf][j];
            uint4 w = *(const uint4*)(Wb + (size_t)(unsigned)ij * 768u);
            for (;;) {
                int j2 = j + 6;
                bool more = j2 < cnt;
                int ij2 = 0; float pj2 = 0.f; uint4 w2;
                if (more) {
                    ij2 = Ii[j2];
                    pj2 = Pp[hf][j2];
                    w2 = *(const uint4*)(Wb + (size_t)(unsigned)ij2 * 768u);
                }
                f32x2 pv; pv.x = pj; pv.y = pj;
                acc[0] = pkfma(cvt8<false>(w.x), pv, acc[0]);
                acc[1] = pkfma(cvt8<true>(w.x),  pv, acc[1]);
                acc[2] = pkfma(cvt8<false>(w.y), pv, acc[2]);
                acc[3] = pkfma(cvt8<true>(w.y),  pv, acc[3]);
                acc[4] = pkfma(cvt8<false>(w.z), pv, acc[4]);
                acc[5] = pkfma(cvt8<true>(w.z),  pv, acc[5]);
                acc[6] = pkfma(cvt8<false>(w.w), pv, acc[6]);
                acc[7] = pkfma(cvt8<true>(w.w),  pv, acc[7]);
                if (!more) break;
                j = j2; pj = pj2; w = w2;
            }
        }
    }

    if (lane < 48) {
#pragma unroll
        for (int k = 0; k < 8; k++)
            *(f32x2*)&part[wv * 768 + lane * 16 + 2 * k] = acc[k];
    }
    __syncthreads();
    for (int f = t; f < 768; f += 384) {
        float sx = 0.f;
#pragma unroll
        for (int w6 = 0; w6 < 6; w6++) sx += part[w6 * 768 + f];
        part[f] = sx;
    }
    __syncthreads();
    if (t < 121) {
        float tot = 0.f;
#pragma unroll
        for (int hh = 0; hh < 6; hh++) tot += part[hh * 128 + t];
        tot *= (1.f / 6.f);
        out[(size_t)n * 121 + t] = 1.f / (1.f + __expf(-tot));
    }
}

extern "C" void kernel_launch(void* const* d_in, const int* in_sizes, int n_in,
                              void* d_out, int out_size, void* d_ws, size_t ws_size,
                              hipStream_t stream) {
    const float* x  = (const float*)d_in[0];
    const int*   ei = (const int*)d_in[1];
    const float* W1 = (const float*)d_in[2];
    const float* a1 = (const float*)d_in[3];
    const float* W2 = (const float*)d_in[4];
    const float* a2 = (const float*)d_in[5];
    const float* W3 = (const float*)d_in[6];
    const float* a3 = (const float*)d_in[7];
    float* out = (float*)d_out;
    const int N = N_NODES, E = N_EDGES;
    const int* src = ei;
    const int* dst = ei + E;

    char* ws = (char*)d_ws;
    size_t off = 0;
    auto alloc = [&](size_t b) { size_t o = off; off += (b + 255) & ~(size_t)255; return o; };
    _Float16* X16  = (_Float16*)(ws + alloc((size_t)MPAD * 1024 * 2));  // x1 then x2 (fp16)
    unsigned char* WH8 = (unsigned char*)(ws + alloc((size_t)MPAD * 1024)); // per-layer Wh (fp8)
    _Float16* BT16 = (_Float16*)(ws + alloc((size_t)BT_ROWS * 1024 * 2));
    _Float16* A1   = (_Float16*)(ws + alloc((size_t)MPAD * 64 * 2));
    _Float16* BT1  = (_Float16*)(ws + alloc((size_t)BT_ROWS * 64 * 2));
    float* SPRE   = (float*)(ws + alloc((size_t)12 * N * 4));
    int*   rowptr = (int*)(ws + alloc((size_t)(N + 1) * 4));
    int*   cursor = (int*)(ws + alloc((size_t)N * 4));
    int*   counts = (int*)(ws + alloc((size_t)N * 4));
    int*   excl   = (int*)(ws + alloc((size_t)N * 4));
    int*   partial= (int*)(ws + alloc((size_t)SCAN_BLKS * 4));
    int*   esrc   = (int*)(ws + alloc((size_t)E * 4));

    // CSR by dst
    hipMemsetAsync(counts, 0, (size_t)N * 4, stream);
    hist_kernel<<<(E + 255) / 256, 256, 0, stream>>>(dst, counts, E);
    scan1_kernel<<<SCAN_BLKS, 256, 0, stream>>>(counts, excl, partial, N);
    scan2_kernel<<<1, 128, 0, stream>>>(partial);
    scan3_kernel<<<SCAN_BLKS, 256, 0, stream>>>(excl, partial, rowptr, cursor, N, E);
    scatter_kernel<<<(E + 255) / 256, 256, 0, stream>>>(src, dst, cursor, esrc, E);
    hipMemsetAsync(X16 + (size_t)N * 1024, 0, (size_t)(MPAD - N) * 1024 * 2, stream);

    // ---- layer 1: 50 -> 4x256 concat ----
    pack_x16<<<MPAD * 64 / 256, 256, 0, stream>>>(x, A1);
    pack_bt1<<<1024 * 64 / 256, 256, 0, stream>>>(W1, BT1);
    wtilde_kernel<<<dim3(64, 8), 64, 0, stream>>>(W1, a1, BT1, 50, 64, 256, 4, 1024, 0);
    gemm_f16<<<8 * RHI * 9, 256, 0, stream>>>(A1, BT1, WH8, SPRE, N, 1024, 1024, 64, 9, 0);
    attagg256_kernel<<<N, 256, 0, stream>>>(rowptr, esrc, SPRE, WH8, X16, 0, N);

    // ---- layer 2: 1024 -> 4x256 concat + skip ----
    pack_bt16<<<dim3(4, 1024), 256, 0, stream>>>(W2, BT16, 256, 256, 1024);
    wtilde_kernel<<<dim3(1024, 8), 64, 0, stream>>>(W2, a2, BT16, 1024, 1024, 256, 4, 1024, 0);
    gemm_f16<<<8 * RHI * 9, 256, 0, stream>>>(X16, BT16, WH8, SPRE, N, 1024, 1024, 1024, 9, 0);
    attagg256_kernel<<<N, 256, 0, stream>>>(rowptr, esrc, SPRE, WH8, X16, 1, N);

    // ---- layer 3: 1024 -> 6 heads @ stride 128 (Fout=121 + pad), mean + sigmoid ----
    pack_bt16<<<dim3(4, 768), 256, 0, stream>>>(W3, BT16, 121, 128, 768);
    wtilde_kernel<<<dim3(1024, 12), 64, 0, stream>>>(W3, a3, BT16, 1024, 1024, 121, 6, 768, 1);
    gemm_f16<<<8 * RHI * 6, 256, 0, stream>>>(X16, BT16, WH8, SPRE, N, 768, 768, 1024, 6, 1);
    attagg726_kernel<<<N, 384, 0, stream>>>(rowptr, esrc, SPRE, WH8, out, N);
}

// Round 4
// 462.876 us; speedup vs baseline: 1.0043x; 1.0043x over previous
//
#include <hip/hip_runtime.h>
#include <cstdint>

#define N_NODES 20000
#define N_EDGES 320000
#define ALPHA 0.2f
#define GAT_EPS 1e-16f
#define MPAD 20096           // 157 * 128
#define RBLK 157
#define RHI 20               // ceil(157/8)
#define SCAN_BLKS 80
#define BT_ROWS 1152         // 9 col-blocks * 128

typedef __attribute__((ext_vector_type(8))) _Float16 half8;
typedef __attribute__((ext_vector_type(4))) _Float16 half4t;
typedef __attribute__((ext_vector_type(16))) float f32x16;
typedef __attribute__((ext_vector_type(2))) float f32x2;

__device__ __forceinline__ float elu1(float x) { return x > 0.f ? x : __expf(x) - 1.f; }

__device__ __forceinline__ unsigned char f2fp8(float x) {
    return (unsigned char)(__builtin_amdgcn_cvt_pk_fp8_f32(x, 0.f, 0, false) & 0xff);
}

__device__ __forceinline__ void async16(const void* g, void* l) {
    __builtin_amdgcn_global_load_lds(
        (const __attribute__((address_space(1))) unsigned int*)g,
        (__attribute__((address_space(3))) unsigned int*)l, 16, 0, 0);
}

__device__ __forceinline__ float rdlanef(float v, int j) {
    return __int_as_float(__builtin_amdgcn_readlane(__float_as_int(v), j));
}

// ---------------- CSR build ----------------
__global__ void hist_kernel(const int* __restrict__ dst, int* __restrict__ counts, int E) {
    int e = blockIdx.x * blockDim.x + threadIdx.x;
    if (e < E) atomicAdd(&counts[dst[e]], 1);
}

__global__ void scan1_kernel(const int* __restrict__ counts, int* __restrict__ excl,
                             int* __restrict__ partial, int N) {
    __shared__ int sh[256];
    int t = threadIdx.x, b = blockIdx.x;
    int i = b * 256 + t;
    int v = (i < N) ? counts[i] : 0;
    sh[t] = v;
    __syncthreads();
    for (int d = 1; d < 256; d <<= 1) {
        int x = (t >= d) ? sh[t - d] : 0;
        __syncthreads();
        sh[t] += x;
        __syncthreads();
    }
    if (i < N) excl[i] = sh[t] - v;
    if (t == 255) partial[b] = sh[255];
}

__global__ void scan2_kernel(int* __restrict__ partial) {
    __shared__ int sh[128];
    int t = threadIdx.x;
    int v = (t < SCAN_BLKS) ? partial[t] : 0;
    sh[t] = v;
    __syncthreads();
    for (int d = 1; d < 128; d <<= 1) {
        int x = (t >= d) ? sh[t - d] : 0;
        __syncthreads();
        sh[t] += x;
        __syncthreads();
    }
    if (t < SCAN_BLKS) partial[t] = sh[t] - v;
}

__global__ void scan3_kernel(const int* __restrict__ excl, const int* __restrict__ partial,
                             int* __restrict__ rowptr, int* __restrict__ cursor, int N, int E) {
    int t = threadIdx.x, b = blockIdx.x;
    int i = b * 256 + t;
    if (i < N) {
        int v = excl[i] + partial[b];
        rowptr[i] = v;
        cursor[i] = v;
    }
    if (i == 0) rowptr[N] = E;
}

__global__ void scatter_kernel(const int* __restrict__ src, const int* __restrict__ dst,
                               int* __restrict__ cursor, int* __restrict__ esrc, int E) {
    int e = blockIdx.x * blockDim.x + threadIdx.x;
    if (e < E) {
        int p = atomicAdd(&cursor[dst[e]], 1);
        esrc[p] = src[e];
    }
}

// ---------------- packs ----------------
__global__ void pack_x16(const float* __restrict__ x, _Float16* __restrict__ A) {
    int idx = blockIdx.x * 256 + threadIdx.x;   // MPAD*64
    int r = idx >> 6, c = idx & 63;
    float v = (r < N_NODES && c < 50) ? x[r * 50 + c] : 0.f;
    A[idx] = (_Float16)v;
}

__global__ void pack_bt1(const float* __restrict__ W, _Float16* __restrict__ Bt) {
    int idx = blockIdx.x * 256 + threadIdx.x;   // 1024*64
    int c = idx >> 6, k = idx & 63;
    int h = c >> 8, f = c & 255;
    float v = (k < 50) ? W[((size_t)h * 50 + k) * 256 + f] : 0.f;
    Bt[idx] = (_Float16)v;
}

// generic: BT row c -> head h=c/Fpad, col f=c%Fpad; zero for f>=F (alignment pad)
__global__ void pack_bt16(const float* __restrict__ W, _Float16* __restrict__ Bt,
                          int F, int Fpad, int Ctot) {
    int c = blockIdx.y;
    int k = blockIdx.x * blockDim.x + threadIdx.x;
    float v = 0.f;
    if (c < Ctot) {
        int h = c / Fpad, f = c - h * Fpad;
        if (f < F) v = W[(size_t)h * 1024 * F + (size_t)k * F + f];
    }
    Bt[(size_t)c * 1024 + k] = (_Float16)v;
}

// W~ cols appended at BT rows [Nfeat, Nfeat+2H); gridDim.y MUST be 2*H.
__global__ __launch_bounds__(64) void wtilde_kernel(const float* __restrict__ W,
                                                    const float* __restrict__ a,
                                                    _Float16* __restrict__ BT, int Kreal,
                                                    int Kdim, int F, int H, int Nfeat) {
    int k = blockIdx.x, j = blockIdx.y;
    if (j >= 2 * H) return;
    int lane = threadIdx.x;
    int h = j < H ? j : j - H;
    int ao = j < H ? 0 : F;
    float s = 0.f;
    if (k < Kreal) {
        const float* wp = W + ((size_t)h * Kreal + k) * F;
        const float* ap = a + (size_t)h * 2 * F + ao;
        for (int f = lane; f < F; f += 64) s += wp[f] * ap[f];
    }
#pragma unroll
    for (int off = 32; off; off >>= 1) s += __shfl_down(s, off);
    if (lane == 0) BT[(size_t)(Nfeat + j) * Kdim + k] = (_Float16)s;
}

// ---------------- fp16 MFMA GEMM (32x32x16) -> fp8 Wh + fp32 score cols ----------------
// 2-phase pipelined (double-buffered LDS, next-tile global_load_lds issued before MFMA).
__global__ __launch_bounds__(256) void gemm_f16(const _Float16* __restrict__ A,
                                                const _Float16* __restrict__ BT,
                                                unsigned char* __restrict__ C8,
                                                float* __restrict__ SPRE,
                                                int M, int Nfeat, int ld, int Kdim, int Cblk) {
    int id = blockIdx.x;
    int xm = id & 7, q = id >> 3;
    int cb = q % Cblk, rh = q / Cblk;
    int rb = rh * 8 + xm;
    if (rb >= RBLK) return;
    __shared__ __align__(16) _Float16 sA[2][128 * 64];
    __shared__ __align__(16) _Float16 sB[2][128 * 64];
    int t = threadIdx.x;
    int row0 = rb * 128, col0 = cb * 128;
    int lane = t & 63, wave = t >> 6;
    int wm = wave >> 1, wn = wave & 1;
    int l31 = lane & 31;
    int lhi = lane >> 5;

    const _Float16* gA = A + (size_t)row0 * Kdim;
    const _Float16* gB = BT + (size_t)col0 * Kdim;

    int sR[4], sgl[4];
#pragma unroll
    for (int i = 0; i < 4; i++) {
        int m = i * 256 + t;
        sR[i] = m >> 3;
        sgl[i] = (m & 7) ^ (sR[i] & 7);
    }

    f32x16 acc[2][2] = {};

    // prologue: stage K-tile 0 into buffer 0
#pragma unroll
    for (int i = 0; i < 4; i++) {
        const _Float16* pa = gA + (size_t)sR[i] * Kdim + sgl[i] * 8;
        const _Float16* pb = gB + (size_t)sR[i] * Kdim + sgl[i] * 8;
        async16(pa, &sA[0][(i * 256 + t) * 8]);
        async16(pb, &sB[0][(i * 256 + t) * 8]);
    }

    int cur = 0;
    for (int k0 = 0; k0 < Kdim; k0 += 64) {
        __syncthreads();           // drains vmcnt: buf[cur] staged; prev buf's ds_reads done
        int nxt = k0 + 64;
        if (nxt < Kdim) {
            int nb = cur ^ 1;      // issue next tile's loads BEFORE compute
#pragma unroll
            for (int i = 0; i < 4; i++) {
                const _Float16* pa = gA + (size_t)sR[i] * Kdim + nxt + sgl[i] * 8;
                const _Float16* pb = gB + (size_t)sR[i] * Kdim + nxt + sgl[i] * 8;
                async16(pa, &sA[nb][(i * 256 + t) * 8]);
                async16(pb, &sB[nb][(i * 256 + t) * 8]);
            }
        }
        const _Float16* cA = sA[cur];
        const _Float16* cB = sB[cur];
#pragma unroll
        for (int kk = 0; kk < 4; kk++) {
            int g = kk * 2 + lhi;
            half8 af[2], bf[2];
#pragma unroll
            for (int mt = 0; mt < 2; mt++) {
                int R = wm * 64 + mt * 32 + l31;
                int gp = g ^ (R & 7);
                af[mt] = *(const half8*)(cA + R * 64 + gp * 8);
            }
#pragma unroll
            for (int nt = 0; nt < 2; nt++) {
                int R = wn * 64 + nt * 32 + l31;
                int gp = g ^ (R & 7);
                bf[nt] = *(const half8*)(cB + R * 64 + gp * 8);
            }
#pragma unroll
            for (int mt = 0; mt < 2; mt++)
#pragma unroll
                for (int nt = 0; nt < 2; nt++)
                    acc[mt][nt] = __builtin_amdgcn_mfma_f32_32x32x16_f16(af[mt], bf[nt], acc[mt][nt], 0, 0, 0);
        }
        cur ^= 1;
    }

    int cb32 = col0 + wn * 64 + l31;
    int rb32 = row0 + wm * 64 + 4 * lhi;
#pragma unroll
    for (int mt = 0; mt < 2; mt++)
#pragma unroll
        for (int nt = 0; nt < 2; nt++) {
            int gc = cb32 + nt * 32;
            if (gc < Nfeat) {
#pragma unroll
                for (int r = 0; r < 16; r++) {
                    int gr = rb32 + mt * 32 + (r & 3) + 8 * (r >> 2);
                    if (gr < M) C8[(size_t)gr * ld + gc] = f2fp8(acc[mt][nt][r]);
                }
            } else if (gc < Nfeat + 12) {
                int j = gc - Nfeat;
#pragma unroll
                for (int r = 0; r < 16; r++) {
                    int gr = rb32 + mt * 32 + (r & 3) + 8 * (r >> 2);
                    if (gr < M) SPRE[(size_t)j * N_NODES + gr] = acc[mt][nt][r];
                }
            }
        }
}

// ---------------- fused attention + aggregation, Fout=256 layers ----------------
// block = node, wave = head. Phase 1: lanes over edges, per-lane online (m,s), then
// MAX-THEN-SUM cross-lane reduce (6x shfl+max, 1 exp rescale, 6x shfl+add) instead of
// the 2x-exp online merge per step. ptil = lane's rescaled mass == unnormalized p for
// single-chunk nodes (deg<=64 ~ all of them) -> phase-2 exp skipped.
// Phase 2: per-edge (p, idx) broadcast via v_readlane (SGPR feeds v_fmac directly).
__global__ __launch_bounds__(256) void attagg256_kernel(const int* __restrict__ rowptr,
                                                        const int* __restrict__ esrc,
                                                        const float* __restrict__ SPRE,
                                                        const unsigned char* __restrict__ WH8,
                                                        _Float16* __restrict__ X16,
                                                        int use_skip, int N) {
    int n = blockIdx.x;
    int h = threadIdx.x >> 6;
    int lane = threadIdx.x & 63;
    int start = rowptr[n], end = rowptr[n + 1];
    const float* ss = SPRE + (size_t)h * N;
    float sd = SPRE[(size_t)(4 + h) * N + n];

    // ---- phase 1 ----
    float m = -1e30f, s = 0.f;
    int sidx = 0; float ssc = -1e30f;   // last chunk's per-lane (idx, score)
    for (int e0 = start; e0 < end; e0 += 64) {
        int e = e0 + lane;
        bool act = e < end;
        int idx = act ? esrc[e] : 0;
        float sc = -1e30f;
        if (act) {
            sc = ss[idx] + sd;
            sc = sc > 0.f ? sc : ALPHA * sc;
        }
        sidx = idx; ssc = sc;
        float mn = fmaxf(m, sc);
        s = s * __expf(m - mn) + (act ? __expf(sc - mn) : 0.f);
        m = mn;
    }
    float lm = m;
#pragma unroll
    for (int off = 1; off < 64; off <<= 1) m = fmaxf(m, __shfl_xor(m, off));
    float ptil = s * __expf(lm - m);    // unnormalized per-edge p iff single chunk
    s = ptil;
#pragma unroll
    for (int off = 1; off < 64; off <<= 1) s += __shfl_xor(s, off);
    float inv = 1.f / (s + GAT_EPS);
    bool single = (end - start) <= 64;

    // ---- phase 2 ----
    const unsigned char* Wb = WH8 + h * 256 + lane * 4;
    float a0 = 0.f, a1 = 0.f, a2 = 0.f, a3 = 0.f;
    int lastStart = start + (((end - start - 1) >> 6) << 6);   // valid when end>start
    for (int e0 = start; e0 < end; e0 += 64) {
        int e = e0 + lane;
        bool act = e < end;
        int idx; float p;
        if (e0 == lastStart) {
            idx = sidx;
            p = act ? (single ? ptil * inv : __expf(ssc - m) * inv) : 0.f;
        } else {
            idx = act ? esrc[e] : 0;
            float sc = -1e30f;
            if (act) {
                sc = ss[idx] + sd;
                sc = sc > 0.f ? sc : ALPHA * sc;
            }
            p = act ? __expf(sc - m) * inv : 0.f;
        }
        int cnt = end - e0; if (cnt > 64) cnt = 64;
        int j = 0;
        for (; j + 4 <= cnt; j += 4) {
            int i0 = __builtin_amdgcn_readlane(idx, j);
            int i1 = __builtin_amdgcn_readlane(idx, j + 1);
            int i2 = __builtin_amdgcn_readlane(idx, j + 2);
            int i3 = __builtin_amdgcn_readlane(idx, j + 3);
            float p0 = rdlanef(p, j), p1 = rdlanef(p, j + 1);
            float p2 = rdlanef(p, j + 2), p3 = rdlanef(p, j + 3);
            unsigned int w0 = *(const unsigned int*)(Wb + (size_t)i0 * 1024);
            unsigned int w1 = *(const unsigned int*)(Wb + (size_t)i1 * 1024);
            unsigned int w2 = *(const unsigned int*)(Wb + (size_t)i2 * 1024);
            unsigned int w3 = *(const unsigned int*)(Wb + (size_t)i3 * 1024);
            f32x2 l0 = __builtin_amdgcn_cvt_pk_f32_fp8((int)w0, false);
            f32x2 h0v = __builtin_amdgcn_cvt_pk_f32_fp8((int)w0, true);
            f32x2 l1 = __builtin_amdgcn_cvt_pk_f32_fp8((int)w1, false);
            f32x2 h1v = __builtin_amdgcn_cvt_pk_f32_fp8((int)w1, true);
            f32x2 l2 = __builtin_amdgcn_cvt_pk_f32_fp8((int)w2, false);
            f32x2 h2v = __builtin_amdgcn_cvt_pk_f32_fp8((int)w2, true);
            f32x2 l3 = __builtin_amdgcn_cvt_pk_f32_fp8((int)w3, false);
            f32x2 h3v = __builtin_amdgcn_cvt_pk_f32_fp8((int)w3, true);
            a0 += p0 * l0.x + p1 * l1.x + p2 * l2.x + p3 * l3.x;
            a1 += p0 * l0.y + p1 * l1.y + p2 * l2.y + p3 * l3.y;
            a2 += p0 * h0v.x + p1 * h1v.x + p2 * h2v.x + p3 * h3v.x;
            a3 += p0 * h0v.y + p1 * h1v.y + p2 * h2v.y + p3 * h3v.y;
        }
        for (; j < cnt; j++) {
            int ij = __builtin_amdgcn_readlane(idx, j);
            float pj = rdlanef(p, j);
            unsigned int w = *(const unsigned int*)(Wb + (size_t)ij * 1024);
            f32x2 lo = __builtin_amdgcn_cvt_pk_f32_fp8((int)w, false);
            f32x2 hi = __builtin_amdgcn_cvt_pk_f32_fp8((int)w, true);
            a0 += pj * lo.x; a1 += pj * lo.y; a2 += pj * hi.x; a3 += pj * hi.y;
        }
    }

    size_t o = (size_t)n * 1024 + h * 256 + lane * 4;
    float v0, v1, v2, v3;
    if (use_skip) {
        half4t sk = *(const half4t*)(X16 + o);
        v0 = elu1(elu1(a0) + (float)sk.x);
        v1 = elu1(elu1(a1) + (float)sk.y);
        v2 = elu1(elu1(a2) + (float)sk.z);
        v3 = elu1(elu1(a3) + (float)sk.w);
    } else {
        v0 = elu1(elu1(a0)); v1 = elu1(elu1(a1));
        v2 = elu1(elu1(a2)); v3 = elu1(elu1(a3));
    }
    half4t r;
    r.x = (_Float16)v0; r.y = (_Float16)v1; r.z = (_Float16)v2; r.w = (_Float16)v3;
    *(half4t*)(X16 + o) = r;
}

// ---------------- fused attention + aggregation, layer 3 (6 heads, Fout=121) ----------
// block = node, 6 waves = 6 heads. Same max-then-sum reduce; phase 2: lanes 0..61
// gather uchar2 at h*124 + 2*lane (pad cols 121..123 are exact GEMM zeros).
__global__ __launch_bounds__(384) void attagg726_kernel(const int* __restrict__ rowptr,
                                                        const int* __restrict__ esrc,
                                                        const float* __restrict__ SPRE,
                                                        const unsigned char* __restrict__ WH8,
                                                        float* __restrict__ out, int N) {
    __shared__ float part[6][124];
    int n = blockIdx.x;
    int t = threadIdx.x;
    int h = t >> 6;
    int lane = t & 63;
    int start = rowptr[n], end = rowptr[n + 1];
    const float* ss = SPRE + (size_t)h * N;
    float sd = SPRE[(size_t)(6 + h) * N + n];

    float m = -1e30f, s = 0.f;
    int sidx = 0; float ssc = -1e30f;
    for (int e0 = start; e0 < end; e0 += 64) {
        int e = e0 + lane;
        bool act = e < end;
        int idx = act ? esrc[e] : 0;
        float sc = -1e30f;
        if (act) {
            sc = ss[idx] + sd;
            sc = sc > 0.f ? sc : ALPHA * sc;
        }
        sidx = idx; ssc = sc;
        float mn = fmaxf(m, sc);
        s = s * __expf(m - mn) + (act ? __expf(sc - mn) : 0.f);
        m = mn;
    }
    float lm = m;
#pragma unroll
    for (int off = 1; off < 64; off <<= 1) m = fmaxf(m, __shfl_xor(m, off));
    float ptil = s * __expf(lm - m);
    s = ptil;
#pragma unroll
    for (int off = 1; off < 64; off <<= 1) s += __shfl_xor(s, off);
    float inv = 1.f / (s + GAT_EPS);
    bool single = (end - start) <= 64;

    const unsigned char* Wb = WH8 + h * 124 + 2 * lane;
    float a0 = 0.f, a1 = 0.f;
    int lastStart = start + (((end - start - 1) >> 6) << 6);
    for (int e0 = start; e0 < end; e0 += 64) {
        int e = e0 + lane;
        bool act = e < end;
        int idx; float p;
        if (e0 == lastStart) {
            idx = sidx;
            p = act ? (single ? ptil * inv : __expf(ssc - m) * inv) : 0.f;
        } else {
            idx = act ? esrc[e] : 0;
            float sc = -1e30f;
            if (act) {
                sc = ss[idx] + sd;
                sc = sc > 0.f ? sc : ALPHA * sc;
            }
            p = act ? __expf(sc - m) * inv : 0.f;
        }
        int cnt = end - e0; if (cnt > 64) cnt = 64;
        if (lane < 62) {
            int j = 0;
            for (; j + 4 <= cnt; j += 4) {
                int i0 = __builtin_amdgcn_readlane(idx, j);
                int i1 = __builtin_amdgcn_readlane(idx, j + 1);
                int i2 = __builtin_amdgcn_readlane(idx, j + 2);
                int i3 = __builtin_amdgcn_readlane(idx, j + 3);
                float p0 = rdlanef(p, j), p1 = rdlanef(p, j + 1);
                float p2 = rdlanef(p, j + 2), p3 = rdlanef(p, j + 3);
                unsigned short w0 = *(const unsigned short*)(Wb + (size_t)i0 * 768);
                unsigned short w1 = *(const unsigned short*)(Wb + (size_t)i1 * 768);
                unsigned short w2 = *(const unsigned short*)(Wb + (size_t)i2 * 768);
                unsigned short w3 = *(const unsigned short*)(Wb + (size_t)i3 * 768);
                f32x2 f0 = __builtin_amdgcn_cvt_pk_f32_fp8((int)w0, false);
                f32x2 f1 = __builtin_amdgcn_cvt_pk_f32_fp8((int)w1, false);
                f32x2 f2 = __builtin_amdgcn_cvt_pk_f32_fp8((int)w2, false);
                f32x2 f3 = __builtin_amdgcn_cvt_pk_f32_fp8((int)w3, false);
                a0 += p0 * f0.x + p1 * f1.x + p2 * f2.x + p3 * f3.x;
                a1 += p0 * f0.y + p1 * f1.y + p2 * f2.y + p3 * f3.y;
            }
            for (; j < cnt; j++) {
                int ij = __builtin_amdgcn_readlane(idx, j);
                float pj = rdlanef(p, j);
                unsigned short w = *(const unsigned short*)(Wb + (size_t)ij * 768);
                f32x2 f = __builtin_amdgcn_cvt_pk_f32_fp8((int)w, false);
                a0 += pj * f.x; a1 += pj * f.y;
            }
        }
    }
    if (lane < 62) {
        part[h][2 * lane]     = a0;
        part[h][2 * lane + 1] = a1;
    }
    __syncthreads();
    if (t < 121) {
        float tot = (part[0][t] + part[1][t] + part[2][t] +
                     part[3][t] + part[4][t] + part[5][t]) * (1.f / 6.f);
        out[(size_t)n * 121 + t] = 1.f / (1.f + __expf(-tot));
    }
}

extern "C" void kernel_launch(void* const* d_in, const int* in_sizes, int n_in,
                              void* d_out, int out_size, void* d_ws, size_t ws_size,
                              hipStream_t stream) {
    const float* x  = (const float*)d_in[0];
    const int*   ei = (const int*)d_in[1];
    const float* W1 = (const float*)d_in[2];
    const float* a1 = (const float*)d_in[3];
    const float* W2 = (const float*)d_in[4];
    const float* a2 = (const float*)d_in[5];
    const float* W3 = (const float*)d_in[6];
    const float* a3 = (const float*)d_in[7];
    float* out = (float*)d_out;
    const int N = N_NODES, E = N_EDGES;
    const int* src = ei;
    const int* dst = ei + E;

    char* ws = (char*)d_ws;
    size_t off = 0;
    auto alloc = [&](size_t b) { size_t o = off; off += (b + 255) & ~(size_t)255; return o; };
    _Float16* X16  = (_Float16*)(ws + alloc((size_t)MPAD * 1024 * 2));  // x1 then x2 (fp16)
    unsigned char* WH8 = (unsigned char*)(ws + alloc((size_t)MPAD * 1024)); // per-layer Wh (fp8)
    _Float16* BT16 = (_Float16*)(ws + alloc((size_t)BT_ROWS * 1024 * 2));
    _Float16* A1   = (_Float16*)(ws + alloc((size_t)MPAD * 64 * 2));
    _Float16* BT1  = (_Float16*)(ws + alloc((size_t)BT_ROWS * 64 * 2));
    float* SPRE   = (float*)(ws + alloc((size_t)12 * N * 4));
    int*   rowptr = (int*)(ws + alloc((size_t)(N + 1) * 4));
    int*   cursor = (int*)(ws + alloc((size_t)N * 4));
    int*   counts = (int*)(ws + alloc((size_t)N * 4));
    int*   excl   = (int*)(ws + alloc((size_t)N * 4));
    int*   partial= (int*)(ws + alloc((size_t)SCAN_BLKS * 4));
    int*   esrc   = (int*)(ws + alloc((size_t)E * 4));

    // CSR by dst
    hipMemsetAsync(counts, 0, (size_t)N * 4, stream);
    hist_kernel<<<(E + 255) / 256, 256, 0, stream>>>(dst, counts, E);
    scan1_kernel<<<SCAN_BLKS, 256, 0, stream>>>(counts, excl, partial, N);
    scan2_kernel<<<1, 128, 0, stream>>>(partial);
    scan3_kernel<<<SCAN_BLKS, 256, 0, stream>>>(excl, partial, rowptr, cursor, N, E);
    scatter_kernel<<<(E + 255) / 256, 256, 0, stream>>>(src, dst, cursor, esrc, E);
    hipMemsetAsync(X16 + (size_t)N * 1024, 0, (size_t)(MPAD - N) * 1024 * 2, stream);

    // ---- layer 1: 50 -> 4x256 concat ----
    pack_x16<<<MPAD * 64 / 256, 256, 0, stream>>>(x, A1);
    pack_bt1<<<1024 * 64 / 256, 256, 0, stream>>>(W1, BT1);
    wtilde_kernel<<<dim3(64, 8), 64, 0, stream>>>(W1, a1, BT1, 50, 64, 256, 4, 1024);
    gemm_f16<<<8 * RHI * 9, 256, 0, stream>>>(A1, BT1, WH8, SPRE, N, 1024, 1024, 64, 9);
    attagg256_kernel<<<N, 256, 0, stream>>>(rowptr, esrc, SPRE, WH8, X16, 0, N);

    // ---- layer 2: 1024 -> 4x256 concat + skip ----
    pack_bt16<<<dim3(4, 1024), 256, 0, stream>>>(W2, BT16, 256, 256, 1024);
    wtilde_kernel<<<dim3(1024, 8), 64, 0, stream>>>(W2, a2, BT16, 1024, 1024, 256, 4, 1024);
    gemm_f16<<<8 * RHI * 9, 256, 0, stream>>>(X16, BT16, WH8, SPRE, N, 1024, 1024, 1024, 9);
    attagg256_kernel<<<N, 256, 0, stream>>>(rowptr, esrc, SPRE, WH8, X16, 1, N);

    // ---- layer 3: 1024 -> 6x121 (stride 124, zero-padded), mean + sigmoid ----
    pack_bt16<<<dim3(4, 744), 256, 0, stream>>>(W3, BT16, 121, 124, 744);
    wtilde_kernel<<<dim3(1024, 12), 64, 0, stream>>>(W3, a3, BT16, 1024, 1024, 121, 6, 744);
    gemm_f16<<<8 * RHI * 6, 256, 0, stream>>>(X16, BT16, WH8, SPRE, N, 744, 768, 1024, 6);
    attagg726_kernel<<<N, 384, 0, stream>>>(rowptr, esrc, SPRE, WH8, out, N);
}

// Round 5
// 448.487 us; speedup vs baseline: 1.0365x; 1.0321x over previous
//
#include <hip/hip_runtime.h>
#include <cstdint>

#define N_NODES 20000
#define N_EDGES 320000
#define ALPHA 0.2f
#define GAT_EPS 1e-16f
#define MPAD 20096           // 157 * 128
#define RBLK 157
#define RHI 20               // ceil(157/8)
#define SCAN_BLKS 80
#define BT_ROWS 1152         // 9 col-blocks * 128

typedef __attribute__((ext_vector_type(8))) _Float16 half8;
typedef __attribute__((ext_vector_type(4))) _Float16 half4t;
typedef __attribute__((ext_vector_type(16))) float f32x16;
typedef __attribute__((ext_vector_type(2))) float f32x2;

__device__ __forceinline__ float elu1(float x) { return x > 0.f ? x : __expf(x) - 1.f; }

__device__ __forceinline__ unsigned char f2fp8(float x) {
    return (unsigned char)(__builtin_amdgcn_cvt_pk_fp8_f32(x, 0.f, 0, false) & 0xff);
}

__device__ __forceinline__ void async16(const void* g, void* l) {
    __builtin_amdgcn_global_load_lds(
        (const __attribute__((address_space(1))) unsigned int*)g,
        (__attribute__((address_space(3))) unsigned int*)l, 16, 0, 0);
}

__device__ __forceinline__ float rdlanef(float v, int j) {
    return __int_as_float(__builtin_amdgcn_readlane(__float_as_int(v), j));
}

// ---------------- CSR build ----------------
__global__ void hist_kernel(const int* __restrict__ dst, int* __restrict__ counts, int E) {
    int e = blockIdx.x * blockDim.x + threadIdx.x;
    if (e < E) atomicAdd(&counts[dst[e]], 1);
}

__global__ void scan1_kernel(const int* __restrict__ counts, int* __restrict__ excl,
                             int* __restrict__ partial, int N) {
    __shared__ int sh[256];
    int t = threadIdx.x, b = blockIdx.x;
    int i = b * 256 + t;
    int v = (i < N) ? counts[i] : 0;
    sh[t] = v;
    __syncthreads();
    for (int d = 1; d < 256; d <<= 1) {
        int x = (t >= d) ? sh[t - d] : 0;
        __syncthreads();
        sh[t] += x;
        __syncthreads();
    }
    if (i < N) excl[i] = sh[t] - v;
    if (t == 255) partial[b] = sh[255];
}

__global__ void scan2_kernel(int* __restrict__ partial) {
    __shared__ int sh[128];
    int t = threadIdx.x;
    int v = (t < SCAN_BLKS) ? partial[t] : 0;
    sh[t] = v;
    __syncthreads();
    for (int d = 1; d < 128; d <<= 1) {
        int x = (t >= d) ? sh[t - d] : 0;
        __syncthreads();
        sh[t] += x;
        __syncthreads();
    }
    if (t < SCAN_BLKS) partial[t] = sh[t] - v;
}

__global__ void scan3_kernel(const int* __restrict__ excl, const int* __restrict__ partial,
                             int* __restrict__ rowptr, int* __restrict__ cursor, int N, int E) {
    int t = threadIdx.x, b = blockIdx.x;
    int i = b * 256 + t;
    if (i < N) {
        int v = excl[i] + partial[b];
        rowptr[i] = v;
        cursor[i] = v;
    }
    if (i == 0) rowptr[N] = E;
}

__global__ void scatter_kernel(const int* __restrict__ src, const int* __restrict__ dst,
                               int* __restrict__ cursor, int* __restrict__ esrc, int E) {
    int e = blockIdx.x * blockDim.x + threadIdx.x;
    if (e < E) {
        int p = atomicAdd(&cursor[dst[e]], 1);
        esrc[p] = src[e];
    }
}

// ---------------- packs ----------------
__global__ void pack_x16(const float* __restrict__ x, _Float16* __restrict__ A) {
    int idx = blockIdx.x * 256 + threadIdx.x;   // MPAD*64
    int r = idx >> 6, c = idx & 63;
    float v = (r < N_NODES && c < 50) ? x[r * 50 + c] : 0.f;
    A[idx] = (_Float16)v;
}

__global__ void pack_bt1(const float* __restrict__ W, _Float16* __restrict__ Bt) {
    int idx = blockIdx.x * 256 + threadIdx.x;   // 1024*64
    int c = idx >> 6, k = idx & 63;
    int h = c >> 8, f = c & 255;
    float v = (k < 50) ? W[((size_t)h * 50 + k) * 256 + f] : 0.f;
    Bt[idx] = (_Float16)v;
}

// generic: BT row c -> head h=c/Fpad, col f=c%Fpad; zero for f>=F (alignment pad)
__global__ void pack_bt16(const float* __restrict__ W, _Float16* __restrict__ Bt,
                          int F, int Fpad, int Ctot) {
    int c = blockIdx.y;
    int k = blockIdx.x * blockDim.x + threadIdx.x;
    float v = 0.f;
    if (c < Ctot) {
        int h = c / Fpad, f = c - h * Fpad;
        if (f < F) v = W[(size_t)h * 1024 * F + (size_t)k * F + f];
    }
    Bt[(size_t)c * 1024 + k] = (_Float16)v;
}

// W~ cols appended at BT rows [Nfeat, Nfeat+2H); gridDim.y MUST be 2*H.
__global__ __launch_bounds__(64) void wtilde_kernel(const float* __restrict__ W,
                                                    const float* __restrict__ a,
                                                    _Float16* __restrict__ BT, int Kreal,
                                                    int Kdim, int F, int H, int Nfeat) {
    int k = blockIdx.x, j = blockIdx.y;
    if (j >= 2 * H) return;
    int lane = threadIdx.x;
    int h = j < H ? j : j - H;
    int ao = j < H ? 0 : F;
    float s = 0.f;
    if (k < Kreal) {
        const float* wp = W + ((size_t)h * Kreal + k) * F;
        const float* ap = a + (size_t)h * 2 * F + ao;
        for (int f = lane; f < F; f += 64) s += wp[f] * ap[f];
    }
#pragma unroll
    for (int off = 32; off; off >>= 1) s += __shfl_down(s, off);
    if (lane == 0) BT[(size_t)(Nfeat + j) * Kdim + k] = (_Float16)s;
}

// ---------------- fp16 MFMA GEMM (32x32x16) -> fp8 Wh + fp32 score cols ----------------
// 2-phase pipelined (double-buffered LDS, next-tile global_load_lds issued before MFMA).
__global__ __launch_bounds__(256) void gemm_f16(const _Float16* __restrict__ A,
                                                const _Float16* __restrict__ BT,
                                                unsigned char* __restrict__ C8,
                                                float* __restrict__ SPRE,
                                                int M, int Nfeat, int ld, int Kdim, int Cblk) {
    int id = blockIdx.x;
    int xm = id & 7, q = id >> 3;
    int cb = q % Cblk, rh = q / Cblk;
    int rb = rh * 8 + xm;
    if (rb >= RBLK) return;
    __shared__ __align__(16) _Float16 sA[2][128 * 64];
    __shared__ __align__(16) _Float16 sB[2][128 * 64];
    int t = threadIdx.x;
    int row0 = rb * 128, col0 = cb * 128;
    int lane = t & 63, wave = t >> 6;
    int wm = wave >> 1, wn = wave & 1;
    int l31 = lane & 31;
    int lhi = lane >> 5;

    const _Float16* gA = A + (size_t)row0 * Kdim;
    const _Float16* gB = BT + (size_t)col0 * Kdim;

    int sR[4], sgl[4];
#pragma unroll
    for (int i = 0; i < 4; i++) {
        int m = i * 256 + t;
        sR[i] = m >> 3;
        sgl[i] = (m & 7) ^ (sR[i] & 7);
    }

    f32x16 acc[2][2] = {};

    // prologue: stage K-tile 0 into buffer 0
#pragma unroll
    for (int i = 0; i < 4; i++) {
        const _Float16* pa = gA + (size_t)sR[i] * Kdim + sgl[i] * 8;
        const _Float16* pb = gB + (size_t)sR[i] * Kdim + sgl[i] * 8;
        async16(pa, &sA[0][(i * 256 + t) * 8]);
        async16(pb, &sB[0][(i * 256 + t) * 8]);
    }

    int cur = 0;
    for (int k0 = 0; k0 < Kdim; k0 += 64) {
        __syncthreads();           // drains vmcnt: buf[cur] staged; prev buf's ds_reads done
        int nxt = k0 + 64;
        if (nxt < Kdim) {
            int nb = cur ^ 1;      // issue next tile's loads BEFORE compute
#pragma unroll
            for (int i = 0; i < 4; i++) {
                const _Float16* pa = gA + (size_t)sR[i] * Kdim + nxt + sgl[i] * 8;
                const _Float16* pb = gB + (size_t)sR[i] * Kdim + nxt + sgl[i] * 8;
                async16(pa, &sA[nb][(i * 256 + t) * 8]);
                async16(pb, &sB[nb][(i * 256 + t) * 8]);
            }
        }
        const _Float16* cA = sA[cur];
        const _Float16* cB = sB[cur];
#pragma unroll
        for (int kk = 0; kk < 4; kk++) {
            int g = kk * 2 + lhi;
            half8 af[2], bf[2];
#pragma unroll
            for (int mt = 0; mt < 2; mt++) {
                int R = wm * 64 + mt * 32 + l31;
                int gp = g ^ (R & 7);
                af[mt] = *(const half8*)(cA + R * 64 + gp * 8);
            }
#pragma unroll
            for (int nt = 0; nt < 2; nt++) {
                int R = wn * 64 + nt * 32 + l31;
                int gp = g ^ (R & 7);
                bf[nt] = *(const half8*)(cB + R * 64 + gp * 8);
            }
#pragma unroll
            for (int mt = 0; mt < 2; mt++)
#pragma unroll
                for (int nt = 0; nt < 2; nt++)
                    acc[mt][nt] = __builtin_amdgcn_mfma_f32_32x32x16_f16(af[mt], bf[nt], acc[mt][nt], 0, 0, 0);
        }
        cur ^= 1;
    }

    int cb32 = col0 + wn * 64 + l31;
    int rb32 = row0 + wm * 64 + 4 * lhi;
#pragma unroll
    for (int mt = 0; mt < 2; mt++)
#pragma unroll
        for (int nt = 0; nt < 2; nt++) {
            int gc = cb32 + nt * 32;
            if (gc < Nfeat) {
#pragma unroll
                for (int r = 0; r < 16; r++) {
                    int gr = rb32 + mt * 32 + (r & 3) + 8 * (r >> 2);
                    if (gr < M) C8[(size_t)gr * ld + gc] = f2fp8(acc[mt][nt][r]);
                }
            } else if (gc < Nfeat + 12) {
                int j = gc - Nfeat;
#pragma unroll
                for (int r = 0; r < 16; r++) {
                    int gr = rb32 + mt * 32 + (r & 3) + 8 * (r >> 2);
                    if (gr < M) SPRE[(size_t)j * N_NODES + gr] = acc[mt][nt][r];
                }
            }
        }
}

// ---------------- fused attention + aggregation, Fout=256 layers ----------------
// block = node, wave = head. FAST path (deg<=64, ~all nodes): per-lane score; the
// W-row gathers for up to 3 groups of 8 edges are ISSUED BEFORE the softmax shuffle
// reduce (addresses depend only on esrc, not on p) so ~16-24 loads are in flight
// while the ~400-cycle reduce chain runs; then a statically-named 3-buffer rotation
// keeps 2 groups in flight through the consume ladder. Fallback keeps the chunked loop.
__global__ __launch_bounds__(256) void attagg256_kernel(const int* __restrict__ rowptr,
                                                        const int* __restrict__ esrc,
                                                        const float* __restrict__ SPRE,
                                                        const unsigned char* __restrict__ WH8,
                                                        _Float16* __restrict__ X16,
                                                        int use_skip, int N) {
    int n = blockIdx.x;
    int h = threadIdx.x >> 6;
    int lane = threadIdx.x & 63;
    int start = rowptr[n], end = rowptr[n + 1];
    int cnt = end - start;
    const float* ss = SPRE + (size_t)h * N;
    float sd = SPRE[(size_t)(4 + h) * N + n];
    const unsigned char* Wb = WH8 + h * 256 + lane * 4;
    float a0 = 0.f, a1 = 0.f, a2 = 0.f, a3 = 0.f;

    if (cnt <= 64) {
        // ---- fast path: single chunk ----
        int e = start + lane;
        bool act = e < end;
        int idx = act ? esrc[e] : 0;

        unsigned int wA[8], wB[8], wC[8];
        auto ISSUE = [&](unsigned int (&buf)[8], int base) {
#pragma unroll
            for (int u = 0; u < 8; u++) {
                int ij = __builtin_amdgcn_readlane(idx, base + u);
                buf[u] = *(const unsigned int*)(Wb + ((size_t)(unsigned)ij << 10));
            }
        };
        ISSUE(wA, 0);
        if (cnt > 8) ISSUE(wB, 8);
        if (cnt > 16) ISSUE(wC, 16);

        float sc = -1e30f;
        if (act) {
            sc = ss[idx] + sd;
            sc = sc > 0.f ? sc : ALPHA * sc;
        }
        float m = sc;
#pragma unroll
        for (int off = 1; off < 64; off <<= 1) m = fmaxf(m, __shfl_xor(m, off));
        float ptil = act ? __expf(sc - m) : 0.f;
        float s = ptil;
#pragma unroll
        for (int off = 1; off < 64; off <<= 1) s += __shfl_xor(s, off);
        float p = ptil * (1.f / (s + GAT_EPS));

        auto CONSUME = [&](unsigned int (&buf)[8], int base) {
#pragma unroll
            for (int u = 0; u < 8; u++) {
                float pj = rdlanef(p, base + u);
                f32x2 lo = __builtin_amdgcn_cvt_pk_f32_fp8((int)buf[u], false);
                f32x2 hi = __builtin_amdgcn_cvt_pk_f32_fp8((int)buf[u], true);
                a0 += pj * lo.x; a1 += pj * lo.y; a2 += pj * hi.x; a3 += pj * hi.y;
            }
        };
        CONSUME(wA, 0);
        if (cnt > 8)  { if (cnt > 24) ISSUE(wA, 24); CONSUME(wB, 8); }
        if (cnt > 16) { if (cnt > 32) ISSUE(wB, 32); CONSUME(wC, 16); }
        if (cnt > 24) { if (cnt > 40) ISSUE(wC, 40); CONSUME(wA, 24); }
        if (cnt > 32) { if (cnt > 48) ISSUE(wA, 48); CONSUME(wB, 32); }
        if (cnt > 40) { if (cnt > 56) ISSUE(wB, 56); CONSUME(wC, 40); }
        if (cnt > 48) CONSUME(wA, 48);
        if (cnt > 56) CONSUME(wB, 56);
    } else {
        // ---- fallback: chunked (deg > 64, vanishingly rare) ----
        float m = -1e30f, s = 0.f;
        int sidx = 0; float ssc = -1e30f;
        for (int e0 = start; e0 < end; e0 += 64) {
            int e = e0 + lane;
            bool act = e < end;
            int idx = act ? esrc[e] : 0;
            float sc = -1e30f;
            if (act) {
                sc = ss[idx] + sd;
                sc = sc > 0.f ? sc : ALPHA * sc;
            }
            sidx = idx; ssc = sc;
            float mn = fmaxf(m, sc);
            s = s * __expf(m - mn) + (act ? __expf(sc - mn) : 0.f);
            m = mn;
        }
        float lm = m;
#pragma unroll
        for (int off = 1; off < 64; off <<= 1) m = fmaxf(m, __shfl_xor(m, off));
        float ptil = s * __expf(lm - m);
        s = ptil;
#pragma unroll
        for (int off = 1; off < 64; off <<= 1) s += __shfl_xor(s, off);
        float inv = 1.f / (s + GAT_EPS);

        int lastStart = start + (((end - start - 1) >> 6) << 6);
        for (int e0 = start; e0 < end; e0 += 64) {
            int e = e0 + lane;
            bool act = e < end;
            int idx; float p;
            if (e0 == lastStart) {
                idx = sidx;
                p = act ? __expf(ssc - m) * inv : 0.f;
            } else {
                idx = act ? esrc[e] : 0;
                float sc = -1e30f;
                if (act) {
                    sc = ss[idx] + sd;
                    sc = sc > 0.f ? sc : ALPHA * sc;
                }
                p = act ? __expf(sc - m) * inv : 0.f;
            }
            int cn = end - e0; if (cn > 64) cn = 64;
            int j = 0;
            for (; j + 4 <= cn; j += 4) {
                int i0 = __builtin_amdgcn_readlane(idx, j);
                int i1 = __builtin_amdgcn_readlane(idx, j + 1);
                int i2 = __builtin_amdgcn_readlane(idx, j + 2);
                int i3 = __builtin_amdgcn_readlane(idx, j + 3);
                float p0 = rdlanef(p, j), p1 = rdlanef(p, j + 1);
                float p2 = rdlanef(p, j + 2), p3 = rdlanef(p, j + 3);
                unsigned int w0 = *(const unsigned int*)(Wb + (size_t)i0 * 1024);
                unsigned int w1 = *(const unsigned int*)(Wb + (size_t)i1 * 1024);
                unsigned int w2 = *(const unsigned int*)(Wb + (size_t)i2 * 1024);
                unsigned int w3 = *(const unsigned int*)(Wb + (size_t)i3 * 1024);
                f32x2 l0 = __builtin_amdgcn_cvt_pk_f32_fp8((int)w0, false);
                f32x2 h0v = __builtin_amdgcn_cvt_pk_f32_fp8((int)w0, true);
                f32x2 l1 = __builtin_amdgcn_cvt_pk_f32_fp8((int)w1, false);
                f32x2 h1v = __builtin_amdgcn_cvt_pk_f32_fp8((int)w1, true);
                f32x2 l2 = __builtin_amdgcn_cvt_pk_f32_fp8((int)w2, false);
                f32x2 h2v = __builtin_amdgcn_cvt_pk_f32_fp8((int)w2, true);
                f32x2 l3 = __builtin_amdgcn_cvt_pk_f32_fp8((int)w3, false);
                f32x2 h3v = __builtin_amdgcn_cvt_pk_f32_fp8((int)w3, true);
                a0 += p0 * l0.x + p1 * l1.x + p2 * l2.x + p3 * l3.x;
                a1 += p0 * l0.y + p1 * l1.y + p2 * l2.y + p3 * l3.y;
                a2 += p0 * h0v.x + p1 * h1v.x + p2 * h2v.x + p3 * h3v.x;
                a3 += p0 * h0v.y + p1 * h1v.y + p2 * h2v.y + p3 * h3v.y;
            }
            for (; j < cn; j++) {
                int ij = __builtin_amdgcn_readlane(idx, j);
                float pj = rdlanef(p, j);
                unsigned int w = *(const unsigned int*)(Wb + (size_t)ij * 1024);
                f32x2 lo = __builtin_amdgcn_cvt_pk_f32_fp8((int)w, false);
                f32x2 hi = __builtin_amdgcn_cvt_pk_f32_fp8((int)w, true);
                a0 += pj * lo.x; a1 += pj * lo.y; a2 += pj * hi.x; a3 += pj * hi.y;
            }
        }
    }

    size_t o = (size_t)n * 1024 + h * 256 + lane * 4;
    float v0, v1, v2, v3;
    if (use_skip) {
        half4t sk = *(const half4t*)(X16 + o);
        v0 = elu1(elu1(a0) + (float)sk.x);
        v1 = elu1(elu1(a1) + (float)sk.y);
        v2 = elu1(elu1(a2) + (float)sk.z);
        v3 = elu1(elu1(a3) + (float)sk.w);
    } else {
        v0 = elu1(elu1(a0)); v1 = elu1(elu1(a1));
        v2 = elu1(elu1(a2)); v3 = elu1(elu1(a3));
    }
    half4t r;
    r.x = (_Float16)v0; r.y = (_Float16)v1; r.z = (_Float16)v2; r.w = (_Float16)v3;
    *(half4t*)(X16 + o) = r;
}

// ---------------- fused attention + aggregation, layer 3 (6 heads, Fout=121) ----------
// Same fast-path pipelining; phase 2 loads are ushort at h*124 + 2*lane (lanes 62/63
// read in-row garbage, discarded at the part[] write; pad cols 121..123 are GEMM zeros).
__global__ __launch_bounds__(384) void attagg726_kernel(const int* __restrict__ rowptr,
                                                        const int* __restrict__ esrc,
                                                        const float* __restrict__ SPRE,
                                                        const unsigned char* __restrict__ WH8,
                                                        float* __restrict__ out, int N) {
    __shared__ float part[6][124];
    int n = blockIdx.x;
    int t = threadIdx.x;
    int h = t >> 6;
    int lane = t & 63;
    int start = rowptr[n], end = rowptr[n + 1];
    int cnt = end - start;
    const float* ss = SPRE + (size_t)h * N;
    float sd = SPRE[(size_t)(6 + h) * N + n];
    const unsigned char* Wb = WH8 + h * 124 + 2 * lane;
    float a0 = 0.f, a1 = 0.f;

    if (cnt <= 64) {
        int e = start + lane;
        bool act = e < end;
        int idx = act ? esrc[e] : 0;

        unsigned short wA[8], wB[8], wC[8];
        auto ISSUE = [&](unsigned short (&buf)[8], int base) {
#pragma unroll
            for (int u = 0; u < 8; u++) {
                int ij = __builtin_amdgcn_readlane(idx, base + u);
                buf[u] = *(const unsigned short*)(Wb + (size_t)(unsigned)ij * 768u);
            }
        };
        ISSUE(wA, 0);
        if (cnt > 8) ISSUE(wB, 8);
        if (cnt > 16) ISSUE(wC, 16);

        float sc = -1e30f;
        if (act) {
            sc = ss[idx] + sd;
            sc = sc > 0.f ? sc : ALPHA * sc;
        }
        float m = sc;
#pragma unroll
        for (int off = 1; off < 64; off <<= 1) m = fmaxf(m, __shfl_xor(m, off));
        float ptil = act ? __expf(sc - m) : 0.f;
        float s = ptil;
#pragma unroll
        for (int off = 1; off < 64; off <<= 1) s += __shfl_xor(s, off);
        float p = ptil * (1.f / (s + GAT_EPS));

        auto CONSUME = [&](unsigned short (&buf)[8], int base) {
#pragma unroll
            for (int u = 0; u < 8; u++) {
                float pj = rdlanef(p, base + u);
                f32x2 f = __builtin_amdgcn_cvt_pk_f32_fp8((int)buf[u], false);
                a0 += pj * f.x; a1 += pj * f.y;
            }
        };
        CONSUME(wA, 0);
        if (cnt > 8)  { if (cnt > 24) ISSUE(wA, 24); CONSUME(wB, 8); }
        if (cnt > 16) { if (cnt > 32) ISSUE(wB, 32); CONSUME(wC, 16); }
        if (cnt > 24) { if (cnt > 40) ISSUE(wC, 40); CONSUME(wA, 24); }
        if (cnt > 32) { if (cnt > 48) ISSUE(wA, 48); CONSUME(wB, 32); }
        if (cnt > 40) { if (cnt > 56) ISSUE(wB, 56); CONSUME(wC, 40); }
        if (cnt > 48) CONSUME(wA, 48);
        if (cnt > 56) CONSUME(wB, 56);
    } else {
        float m = -1e30f, s = 0.f;
        int sidx = 0; float ssc = -1e30f;
        for (int e0 = start; e0 < end; e0 += 64) {
            int e = e0 + lane;
            bool act = e < end;
            int idx = act ? esrc[e] : 0;
            float sc = -1e30f;
            if (act) {
                sc = ss[idx] + sd;
                sc = sc > 0.f ? sc : ALPHA * sc;
            }
            sidx = idx; ssc = sc;
            float mn = fmaxf(m, sc);
            s = s * __expf(m - mn) + (act ? __expf(sc - mn) : 0.f);
            m = mn;
        }
        float lm = m;
#pragma unroll
        for (int off = 1; off < 64; off <<= 1) m = fmaxf(m, __shfl_xor(m, off));
        float ptil = s * __expf(lm - m);
        s = ptil;
#pragma unroll
        for (int off = 1; off < 64; off <<= 1) s += __shfl_xor(s, off);
        float inv = 1.f / (s + GAT_EPS);

        int lastStart = start + (((end - start - 1) >> 6) << 6);
        for (int e0 = start; e0 < end; e0 += 64) {
            int e = e0 + lane;
            bool act = e < end;
            int idx; float p;
            if (e0 == lastStart) {
                idx = sidx;
                p = act ? __expf(ssc - m) * inv : 0.f;
            } else {
                idx = act ? esrc[e] : 0;
                float sc = -1e30f;
                if (act) {
                    sc = ss[idx] + sd;
                    sc = sc > 0.f ? sc : ALPHA * sc;
                }
                p = act ? __expf(sc - m) * inv : 0.f;
            }
            int cn = end - e0; if (cn > 64) cn = 64;
            int j = 0;
            for (; j + 4 <= cn; j += 4) {
                int i0 = __builtin_amdgcn_readlane(idx, j);
                int i1 = __builtin_amdgcn_readlane(idx, j + 1);
                int i2 = __builtin_amdgcn_readlane(idx, j + 2);
                int i3 = __builtin_amdgcn_readlane(idx, j + 3);
                float p0 = rdlanef(p, j), p1 = rdlanef(p, j + 1);
                float p2 = rdlanef(p, j + 2), p3 = rdlanef(p, j + 3);
                unsigned short w0 = *(const unsigned short*)(Wb + (size_t)i0 * 768);
                unsigned short w1 = *(const unsigned short*)(Wb + (size_t)i1 * 768);
                unsigned short w2 = *(const unsigned short*)(Wb + (size_t)i2 * 768);
                unsigned short w3 = *(const unsigned short*)(Wb + (size_t)i3 * 768);
                f32x2 f0 = __builtin_amdgcn_cvt_pk_f32_fp8((int)w0, false);
                f32x2 f1 = __builtin_amdgcn_cvt_pk_f32_fp8((int)w1, false);
                f32x2 f2 = __builtin_amdgcn_cvt_pk_f32_fp8((int)w2, false);
                f32x2 f3 = __builtin_amdgcn_cvt_pk_f32_fp8((int)w3, false);
                a0 += p0 * f0.x + p1 * f1.x + p2 * f2.x + p3 * f3.x;
                a1 += p0 * f0.y + p1 * f1.y + p2 * f2.y + p3 * f3.y;
            }
            for (; j < cn; j++) {
                int ij = __builtin_amdgcn_readlane(idx, j);
                float pj = rdlanef(p, j);
                unsigned short w = *(const unsigned short*)(Wb + (size_t)ij * 768);
                f32x2 f = __builtin_amdgcn_cvt_pk_f32_fp8((int)w, false);
                a0 += pj * f.x; a1 += pj * f.y;
            }
        }
    }

    if (lane < 62) {
        part[h][2 * lane]     = a0;
        part[h][2 * lane + 1] = a1;
    }
    __syncthreads();
    if (t < 121) {
        float tot = (part[0][t] + part[1][t] + part[2][t] +
                     part[3][t] + part[4][t] + part[5][t]) * (1.f / 6.f);
        out[(size_t)n * 121 + t] = 1.f / (1.f + __expf(-tot));
    }
}

extern "C" void kernel_launch(void* const* d_in, const int* in_sizes, int n_in,
                              void* d_out, int out_size, void* d_ws, size_t ws_size,
                              hipStream_t stream) {
    const float* x  = (const float*)d_in[0];
    const int*   ei = (const int*)d_in[1];
    const float* W1 = (const float*)d_in[2];
    const float* a1 = (const float*)d_in[3];
    const float* W2 = (const float*)d_in[4];
    const float* a2 = (const float*)d_in[5];
    const float* W3 = (const float*)d_in[6];
    const float* a3 = (const float*)d_in[7];
    float* out = (float*)d_out;
    const int N = N_NODES, E = N_EDGES;
    const int* src = ei;
    const int* dst = ei + E;

    char* ws = (char*)d_ws;
    size_t off = 0;
    auto alloc = [&](size_t b) { size_t o = off; off += (b + 255) & ~(size_t)255; return o; };
    _Float16* X16  = (_Float16*)(ws + alloc((size_t)MPAD * 1024 * 2));  // x1 then x2 (fp16)
    unsigned char* WH8 = (unsigned char*)(ws + alloc((size_t)MPAD * 1024)); // per-layer Wh (fp8)
    _Float16* BT16 = (_Float16*)(ws + alloc((size_t)BT_ROWS * 1024 * 2));
    _Float16* A1   = (_Float16*)(ws + alloc((size_t)MPAD * 64 * 2));
    _Float16* BT1  = (_Float16*)(ws + alloc((size_t)BT_ROWS * 64 * 2));
    float* SPRE   = (float*)(ws + alloc((size_t)12 * N * 4));
    int*   rowptr = (int*)(ws + alloc((size_t)(N + 1) * 4));
    int*   cursor = (int*)(ws + alloc((size_t)N * 4));
    int*   counts = (int*)(ws + alloc((size_t)N * 4));
    int*   excl   = (int*)(ws + alloc((size_t)N * 4));
    int*   partial= (int*)(ws + alloc((size_t)SCAN_BLKS * 4));
    int*   esrc   = (int*)(ws + alloc((size_t)E * 4));

    // CSR by dst
    hipMemsetAsync(counts, 0, (size_t)N * 4, stream);
    hist_kernel<<<(E + 255) / 256, 256, 0, stream>>>(dst, counts, E);
    scan1_kernel<<<SCAN_BLKS, 256, 0, stream>>>(counts, excl, partial, N);
    scan2_kernel<<<1, 128, 0, stream>>>(partial);
    scan3_kernel<<<SCAN_BLKS, 256, 0, stream>>>(excl, partial, rowptr, cursor, N, E);
    scatter_kernel<<<(E + 255) / 256, 256, 0, stream>>>(src, dst, cursor, esrc, E);
    hipMemsetAsync(X16 + (size_t)N * 1024, 0, (size_t)(MPAD - N) * 1024 * 2, stream);

    // ---- layer 1: 50 -> 4x256 concat ----
    pack_x16<<<MPAD * 64 / 256, 256, 0, stream>>>(x, A1);
    pack_bt1<<<1024 * 64 / 256, 256, 0, stream>>>(W1, BT1);
    wtilde_kernel<<<dim3(64, 8), 64, 0, stream>>>(W1, a1, BT1, 50, 64, 256, 4, 1024);
    gemm_f16<<<8 * RHI * 9, 256, 0, stream>>>(A1, BT1, WH8, SPRE, N, 1024, 1024, 64, 9);
    attagg256_kernel<<<N, 256, 0, stream>>>(rowptr, esrc, SPRE, WH8, X16, 0, N);

    // ---- layer 2: 1024 -> 4x256 concat + skip ----
    pack_bt16<<<dim3(4, 1024), 256, 0, stream>>>(W2, BT16, 256, 256, 1024);
    wtilde_kernel<<<dim3(1024, 8), 64, 0, stream>>>(W2, a2, BT16, 1024, 1024, 256, 4, 1024);
    gemm_f16<<<8 * RHI * 9, 256, 0, stream>>>(X16, BT16, WH8, SPRE, N, 1024, 1024, 1024, 9);
    attagg256_kernel<<<N, 256, 0, stream>>>(rowptr, esrc, SPRE, WH8, X16, 1, N);

    // ---- layer 3: 1024 -> 6x121 (stride 124, zero-padded), mean + sigmoid ----
    pack_bt16<<<dim3(4, 744), 256, 0, stream>>>(W3, BT16, 121, 124, 744);
    wtilde_kernel<<<dim3(1024, 12), 64, 0, stream>>>(W3, a3, BT16, 1024, 1024, 121, 6, 744);
    gemm_f16<<<8 * RHI * 6, 256, 0, stream>>>(X16, BT16, WH8, SPRE, N, 744, 768, 1024, 6);
    attagg726_kernel<<<N, 384, 0, stream>>>(rowptr, esrc, SPRE, WH8, out, N);
}

// Round 6
// 444.528 us; speedup vs baseline: 1.0458x; 1.0089x over previous
//
#include <hip/hip_runtime.h>
#include <cstdint>

#define N_NODES 20000
#define N_EDGES 320000
#define ALPHA 0.2f
#define GAT_EPS 1e-16f
#define MPAD 20096           // 157 * 128
#define RBLK 157
#define RHI 20               // ceil(157/8)
#define SCAN_BLKS 80
#define BT_ROWS 1152         // 9 col-blocks * 128

typedef __attribute__((ext_vector_type(8))) _Float16 half8;
typedef __attribute__((ext_vector_type(4))) _Float16 half4t;
typedef __attribute__((ext_vector_type(16))) float f32x16;
typedef __attribute__((ext_vector_type(2))) float f32x2;

__device__ __forceinline__ float elu1(float x) { return x > 0.f ? x : __expf(x) - 1.f; }

__device__ __forceinline__ unsigned char f2fp8(float x) {
    return (unsigned char)(__builtin_amdgcn_cvt_pk_fp8_f32(x, 0.f, 0, false) & 0xff);
}

__device__ __forceinline__ void async16(const void* g, void* l) {
    __builtin_amdgcn_global_load_lds(
        (const __attribute__((address_space(1))) unsigned int*)g,
        (__attribute__((address_space(3))) unsigned int*)l, 16, 0, 0);
}

__device__ __forceinline__ float rdlanef(float v, int j) {
    return __int_as_float(__builtin_amdgcn_readlane(__float_as_int(v), j));
}

// ---------------- CSR build ----------------
__global__ void hist_kernel(const int* __restrict__ dst, int* __restrict__ counts, int E) {
    int e = blockIdx.x * blockDim.x + threadIdx.x;
    if (e < E) atomicAdd(&counts[dst[e]], 1);
}

__global__ void scan1_kernel(const int* __restrict__ counts, int* __restrict__ excl,
                             int* __restrict__ partial, int N) {
    __shared__ int sh[256];
    int t = threadIdx.x, b = blockIdx.x;
    int i = b * 256 + t;
    int v = (i < N) ? counts[i] : 0;
    sh[t] = v;
    __syncthreads();
    for (int d = 1; d < 256; d <<= 1) {
        int x = (t >= d) ? sh[t - d] : 0;
        __syncthreads();
        sh[t] += x;
        __syncthreads();
    }
    if (i < N) excl[i] = sh[t] - v;
    if (t == 255) partial[b] = sh[255];
}

__global__ void scan2_kernel(int* __restrict__ partial) {
    __shared__ int sh[128];
    int t = threadIdx.x;
    int v = (t < SCAN_BLKS) ? partial[t] : 0;
    sh[t] = v;
    __syncthreads();
    for (int d = 1; d < 128; d <<= 1) {
        int x = (t >= d) ? sh[t - d] : 0;
        __syncthreads();
        sh[t] += x;
        __syncthreads();
    }
    if (t < SCAN_BLKS) partial[t] = sh[t] - v;
}

__global__ void scan3_kernel(const int* __restrict__ excl, const int* __restrict__ partial,
                             int* __restrict__ rowptr, int* __restrict__ cursor, int N, int E) {
    int t = threadIdx.x, b = blockIdx.x;
    int i = b * 256 + t;
    if (i < N) {
        int v = excl[i] + partial[b];
        rowptr[i] = v;
        cursor[i] = v;
    }
    if (i == 0) rowptr[N] = E;
}

__global__ void scatter_kernel(const int* __restrict__ src, const int* __restrict__ dst,
                               int* __restrict__ cursor, int* __restrict__ esrc, int E) {
    int e = blockIdx.x * blockDim.x + threadIdx.x;
    if (e < E) {
        int p = atomicAdd(&cursor[dst[e]], 1);
        esrc[p] = src[e];
    }
}

// ---------------- packs ----------------
__global__ void pack_x16(const float* __restrict__ x, _Float16* __restrict__ A) {
    int idx = blockIdx.x * 256 + threadIdx.x;   // MPAD*64
    int r = idx >> 6, c = idx & 63;
    float v = (r < N_NODES && c < 50) ? x[r * 50 + c] : 0.f;
    A[idx] = (_Float16)v;
}

__global__ void pack_bt1(const float* __restrict__ W, _Float16* __restrict__ Bt) {
    int idx = blockIdx.x * 256 + threadIdx.x;   // 1024*64
    int c = idx >> 6, k = idx & 63;
    int h = c >> 8, f = c & 255;
    float v = (k < 50) ? W[((size_t)h * 50 + k) * 256 + f] : 0.f;
    Bt[idx] = (_Float16)v;
}

// generic: BT row c -> head h=c/Fpad, col f=c%Fpad; zero for f>=F (alignment pad)
__global__ void pack_bt16(const float* __restrict__ W, _Float16* __restrict__ Bt,
                          int F, int Fpad, int Ctot) {
    int c = blockIdx.y;
    int k = blockIdx.x * blockDim.x + threadIdx.x;
    float v = 0.f;
    if (c < Ctot) {
        int h = c / Fpad, f = c - h * Fpad;
        if (f < F) v = W[(size_t)h * 1024 * F + (size_t)k * F + f];
    }
    Bt[(size_t)c * 1024 + k] = (_Float16)v;
}

// W~ cols appended at BT rows [Nfeat, Nfeat+2H); gridDim.y MUST be 2*H.
__global__ __launch_bounds__(64) void wtilde_kernel(const float* __restrict__ W,
                                                    const float* __restrict__ a,
                                                    _Float16* __restrict__ BT, int Kreal,
                                                    int Kdim, int F, int H, int Nfeat) {
    int k = blockIdx.x, j = blockIdx.y;
    if (j >= 2 * H) return;
    int lane = threadIdx.x;
    int h = j < H ? j : j - H;
    int ao = j < H ? 0 : F;
    float s = 0.f;
    if (k < Kreal) {
        const float* wp = W + ((size_t)h * Kreal + k) * F;
        const float* ap = a + (size_t)h * 2 * F + ao;
        for (int f = lane; f < F; f += 64) s += wp[f] * ap[f];
    }
#pragma unroll
    for (int off = 32; off; off >>= 1) s += __shfl_down(s, off);
    if (lane == 0) BT[(size_t)(Nfeat + j) * Kdim + k] = (_Float16)s;
}

// ---------------- fp16 MFMA GEMM (32x32x16) -> fp8 Wh + fp32 score cols ----------------
// Single-buffer 2-barrier structure (r0 baseline, measured 64.9 us / MfmaUtil 31%):
// 32KB LDS keeps ~2-4 blocks/CU; wave-level overlap across blocks beats an explicit
// dbuf (64KB LDS dropped occupancy 26->18% and cost +17% -- r5 post-mortem).
__global__ __launch_bounds__(256) void gemm_f16(const _Float16* __restrict__ A,
                                                const _Float16* __restrict__ BT,
                                                unsigned char* __restrict__ C8,
                                                float* __restrict__ SPRE,
                                                int M, int Nfeat, int ld, int Kdim, int Cblk) {
    int id = blockIdx.x;
    int xm = id & 7, q = id >> 3;
    int cb = q % Cblk, rh = q / Cblk;
    int rb = rh * 8 + xm;
    if (rb >= RBLK) return;
    __shared__ __align__(16) _Float16 sA[128 * 64];
    __shared__ __align__(16) _Float16 sB[128 * 64];
    int t = threadIdx.x;
    int row0 = rb * 128, col0 = cb * 128;
    int lane = t & 63, wave = t >> 6;
    int wm = wave >> 1, wn = wave & 1;
    int l31 = lane & 31;
    int lhi = lane >> 5;

    const _Float16* gA = A + (size_t)row0 * Kdim;
    const _Float16* gB = BT + (size_t)col0 * Kdim;

    int sR[4], sgl[4];
#pragma unroll
    for (int i = 0; i < 4; i++) {
        int m = i * 256 + t;
        sR[i] = m >> 3;
        sgl[i] = (m & 7) ^ (sR[i] & 7);
    }

    f32x16 acc[2][2] = {};

    for (int k0 = 0; k0 < Kdim; k0 += 64) {
        __syncthreads();
#pragma unroll
        for (int i = 0; i < 4; i++) {
            const _Float16* pa = gA + (size_t)sR[i] * Kdim + k0 + sgl[i] * 8;
            const _Float16* pb = gB + (size_t)sR[i] * Kdim + k0 + sgl[i] * 8;
            async16(pa, sA + (i * 256 + t) * 8);
            async16(pb, sB + (i * 256 + t) * 8);
        }
        __syncthreads();
#pragma unroll
        for (int kk = 0; kk < 4; kk++) {
            int g = kk * 2 + lhi;
            half8 af[2], bf[2];
#pragma unroll
            for (int mt = 0; mt < 2; mt++) {
                int R = wm * 64 + mt * 32 + l31;
                int gp = g ^ (R & 7);
                af[mt] = *(const half8*)(sA + R * 64 + gp * 8);
            }
#pragma unroll
            for (int nt = 0; nt < 2; nt++) {
                int R = wn * 64 + nt * 32 + l31;
                int gp = g ^ (R & 7);
                bf[nt] = *(const half8*)(sB + R * 64 + gp * 8);
            }
#pragma unroll
            for (int mt = 0; mt < 2; mt++)
#pragma unroll
                for (int nt = 0; nt < 2; nt++)
                    acc[mt][nt] = __builtin_amdgcn_mfma_f32_32x32x16_f16(af[mt], bf[nt], acc[mt][nt], 0, 0, 0);
        }
    }

    int cb32 = col0 + wn * 64 + l31;
    int rb32 = row0 + wm * 64 + 4 * lhi;
#pragma unroll
    for (int mt = 0; mt < 2; mt++)
#pragma unroll
        for (int nt = 0; nt < 2; nt++) {
            int gc = cb32 + nt * 32;
            if (gc < Nfeat) {
#pragma unroll
                for (int r = 0; r < 16; r++) {
                    int gr = rb32 + mt * 32 + (r & 3) + 8 * (r >> 2);
                    if (gr < M) C8[(size_t)gr * ld + gc] = f2fp8(acc[mt][nt][r]);
                }
            } else if (gc < Nfeat + 12) {
                int j = gc - Nfeat;
#pragma unroll
                for (int r = 0; r < 16; r++) {
                    int gr = rb32 + mt * 32 + (r & 3) + 8 * (r >> 2);
                    if (gr < M) SPRE[(size_t)j * N_NODES + gr] = acc[mt][nt][r];
                }
            }
        }
}

// ---------------- fused attention + aggregation, Fout=256 layers ----------------
// block = node, wave = head. FAST path (deg<=64, ~all nodes): W-row gathers for up to
// 4 groups of 8 edges issued BEFORE the softmax shuffle reduce (addresses depend only
// on esrc) -> ~32 loads in flight during the ~400-cycle reduce; statically-named
// 4-buffer rotation keeps ~24 in flight through the consume ladder.
__global__ __launch_bounds__(256) void attagg256_kernel(const int* __restrict__ rowptr,
                                                        const int* __restrict__ esrc,
                                                        const float* __restrict__ SPRE,
                                                        const unsigned char* __restrict__ WH8,
                                                        _Float16* __restrict__ X16,
                                                        int use_skip, int N) {
    int n = blockIdx.x;
    int h = threadIdx.x >> 6;
    int lane = threadIdx.x & 63;
    int start = rowptr[n], end = rowptr[n + 1];
    int cnt = end - start;
    const float* ss = SPRE + (size_t)h * N;
    float sd = SPRE[(size_t)(4 + h) * N + n];
    const unsigned char* Wb = WH8 + h * 256 + lane * 4;
    float a0 = 0.f, a1 = 0.f, a2 = 0.f, a3 = 0.f;

    if (cnt <= 64) {
        // ---- fast path: single chunk ----
        int e = start + lane;
        bool act = e < end;
        int idx = act ? esrc[e] : 0;

        unsigned int wA[8], wB[8], wC[8], wD[8];
        auto ISSUE = [&](unsigned int (&buf)[8], int base) {
#pragma unroll
            for (int u = 0; u < 8; u++) {
                int ij = __builtin_amdgcn_readlane(idx, base + u);
                buf[u] = *(const unsigned int*)(Wb + ((size_t)(unsigned)ij << 10));
            }
        };
        ISSUE(wA, 0);
        if (cnt > 8)  ISSUE(wB, 8);
        if (cnt > 16) ISSUE(wC, 16);
        if (cnt > 24) ISSUE(wD, 24);

        float sc = -1e30f;
        if (act) {
            sc = ss[idx] + sd;
            sc = sc > 0.f ? sc : ALPHA * sc;
        }
        float m = sc;
#pragma unroll
        for (int off = 1; off < 64; off <<= 1) m = fmaxf(m, __shfl_xor(m, off));
        float ptil = act ? __expf(sc - m) : 0.f;
        float s = ptil;
#pragma unroll
        for (int off = 1; off < 64; off <<= 1) s += __shfl_xor(s, off);
        float p = ptil * (1.f / (s + GAT_EPS));

        auto CONSUME = [&](unsigned int (&buf)[8], int base) {
#pragma unroll
            for (int u = 0; u < 8; u++) {
                float pj = rdlanef(p, base + u);
                f32x2 lo = __builtin_amdgcn_cvt_pk_f32_fp8((int)buf[u], false);
                f32x2 hi = __builtin_amdgcn_cvt_pk_f32_fp8((int)buf[u], true);
                a0 += pj * lo.x; a1 += pj * lo.y; a2 += pj * hi.x; a3 += pj * hi.y;
            }
        };
        CONSUME(wA, 0);
        if (cnt > 8)  { if (cnt > 32) ISSUE(wA, 32); CONSUME(wB, 8); }
        if (cnt > 16) { if (cnt > 40) ISSUE(wB, 40); CONSUME(wC, 16); }
        if (cnt > 24) { if (cnt > 48) ISSUE(wC, 48); CONSUME(wD, 24); }
        if (cnt > 32) { if (cnt > 56) ISSUE(wD, 56); CONSUME(wA, 32); }
        if (cnt > 40) CONSUME(wB, 40);
        if (cnt > 48) CONSUME(wC, 48);
        if (cnt > 56) CONSUME(wD, 56);
    } else {
        // ---- fallback: chunked (deg > 64, vanishingly rare) ----
        float m = -1e30f, s = 0.f;
        int sidx = 0; float ssc = -1e30f;
        for (int e0 = start; e0 < end; e0 += 64) {
            int e = e0 + lane;
            bool act = e < end;
            int idx = act ? esrc[e] : 0;
            float sc = -1e30f;
            if (act) {
                sc = ss[idx] + sd;
                sc = sc > 0.f ? sc : ALPHA * sc;
            }
            sidx = idx; ssc = sc;
            float mn = fmaxf(m, sc);
            s = s * __expf(m - mn) + (act ? __expf(sc - mn) : 0.f);
            m = mn;
        }
        float lm = m;
#pragma unroll
        for (int off = 1; off < 64; off <<= 1) m = fmaxf(m, __shfl_xor(m, off));
        float ptil = s * __expf(lm - m);
        s = ptil;
#pragma unroll
        for (int off = 1; off < 64; off <<= 1) s += __shfl_xor(s, off);
        float inv = 1.f / (s + GAT_EPS);

        int lastStart = start + (((end - start - 1) >> 6) << 6);
        for (int e0 = start; e0 < end; e0 += 64) {
            int e = e0 + lane;
            bool act = e < end;
            int idx; float p;
            if (e0 == lastStart) {
                idx = sidx;
                p = act ? __expf(ssc - m) * inv : 0.f;
            } else {
                idx = act ? esrc[e] : 0;
                float sc = -1e30f;
                if (act) {
                    sc = ss[idx] + sd;
                    sc = sc > 0.f ? sc : ALPHA * sc;
                }
                p = act ? __expf(sc - m) * inv : 0.f;
            }
            int cn = end - e0; if (cn > 64) cn = 64;
            int j = 0;
            for (; j + 4 <= cn; j += 4) {
                int i0 = __builtin_amdgcn_readlane(idx, j);
                int i1 = __builtin_amdgcn_readlane(idx, j + 1);
                int i2 = __builtin_amdgcn_readlane(idx, j + 2);
                int i3 = __builtin_amdgcn_readlane(idx, j + 3);
                float p0 = rdlanef(p, j), p1 = rdlanef(p, j + 1);
                float p2 = rdlanef(p, j + 2), p3 = rdlanef(p, j + 3);
                unsigned int w0 = *(const unsigned int*)(Wb + (size_t)i0 * 1024);
                unsigned int w1 = *(const unsigned int*)(Wb + (size_t)i1 * 1024);
                unsigned int w2 = *(const unsigned int*)(Wb + (size_t)i2 * 1024);
                unsigned int w3 = *(const unsigned int*)(Wb + (size_t)i3 * 1024);
                f32x2 l0 = __builtin_amdgcn_cvt_pk_f32_fp8((int)w0, false);
                f32x2 h0v = __builtin_amdgcn_cvt_pk_f32_fp8((int)w0, true);
                f32x2 l1 = __builtin_amdgcn_cvt_pk_f32_fp8((int)w1, false);
                f32x2 h1v = __builtin_amdgcn_cvt_pk_f32_fp8((int)w1, true);
                f32x2 l2 = __builtin_amdgcn_cvt_pk_f32_fp8((int)w2, false);
                f32x2 h2v = __builtin_amdgcn_cvt_pk_f32_fp8((int)w2, true);
                f32x2 l3 = __builtin_amdgcn_cvt_pk_f32_fp8((int)w3, false);
                f32x2 h3v = __builtin_amdgcn_cvt_pk_f32_fp8((int)w3, true);
                a0 += p0 * l0.x + p1 * l1.x + p2 * l2.x + p3 * l3.x;
                a1 += p0 * l0.y + p1 * l1.y + p2 * l2.y + p3 * l3.y;
                a2 += p0 * h0v.x + p1 * h1v.x + p2 * h2v.x + p3 * h3v.x;
                a3 += p0 * h0v.y + p1 * h1v.y + p2 * h2v.y + p3 * h3v.y;
            }
            for (; j < cn; j++) {
                int ij = __builtin_amdgcn_readlane(idx, j);
                float pj = rdlanef(p, j);
                unsigned int w = *(const unsigned int*)(Wb + (size_t)ij * 1024);
                f32x2 lo = __builtin_amdgcn_cvt_pk_f32_fp8((int)w, false);
                f32x2 hi = __builtin_amdgcn_cvt_pk_f32_fp8((int)w, true);
                a0 += pj * lo.x; a1 += pj * lo.y; a2 += pj * hi.x; a3 += pj * hi.y;
            }
        }
    }

    size_t o = (size_t)n * 1024 + h * 256 + lane * 4;
    float v0, v1, v2, v3;
    if (use_skip) {
        half4t sk = *(const half4t*)(X16 + o);
        v0 = elu1(elu1(a0) + (float)sk.x);
        v1 = elu1(elu1(a1) + (float)sk.y);
        v2 = elu1(elu1(a2) + (float)sk.z);
        v3 = elu1(elu1(a3) + (float)sk.w);
    } else {
        v0 = elu1(elu1(a0)); v1 = elu1(elu1(a1));
        v2 = elu1(elu1(a2)); v3 = elu1(elu1(a3));
    }
    half4t r;
    r.x = (_Float16)v0; r.y = (_Float16)v1; r.z = (_Float16)v2; r.w = (_Float16)v3;
    *(half4t*)(X16 + o) = r;
}

// ---------------- fused attention + aggregation, layer 3 (6 heads, Fout=121) ----------
// Same fast-path pipelining (4-deep); phase 2 loads ushort at h*124 + 2*lane (lanes
// 62/63 read in-row garbage, discarded at the part[] write; pad cols are GEMM zeros).
__global__ __launch_bounds__(384) void attagg726_kernel(const int* __restrict__ rowptr,
                                                        const int* __restrict__ esrc,
                                                        const float* __restrict__ SPRE,
                                                        const unsigned char* __restrict__ WH8,
                                                        float* __restrict__ out, int N) {
    __shared__ float part[6][124];
    int n = blockIdx.x;
    int t = threadIdx.x;
    int h = t >> 6;
    int lane = t & 63;
    int start = rowptr[n], end = rowptr[n + 1];
    int cnt = end - start;
    const float* ss = SPRE + (size_t)h * N;
    float sd = SPRE[(size_t)(6 + h) * N + n];
    const unsigned char* Wb = WH8 + h * 124 + 2 * lane;
    float a0 = 0.f, a1 = 0.f;

    if (cnt <= 64) {
        int e = start + lane;
        bool act = e < end;
        int idx = act ? esrc[e] : 0;

        unsigned short wA[8], wB[8], wC[8], wD[8];
        auto ISSUE = [&](unsigned short (&buf)[8], int base) {
#pragma unroll
            for (int u = 0; u < 8; u++) {
                int ij = __builtin_amdgcn_readlane(idx, base + u);
                buf[u] = *(const unsigned short*)(Wb + (size_t)(unsigned)ij * 768u);
            }
        };
        ISSUE(wA, 0);
        if (cnt > 8)  ISSUE(wB, 8);
        if (cnt > 16) ISSUE(wC, 16);
        if (cnt > 24) ISSUE(wD, 24);

        float sc = -1e30f;
        if (act) {
            sc = ss[idx] + sd;
            sc = sc > 0.f ? sc : ALPHA * sc;
        }
        float m = sc;
#pragma unroll
        for (int off = 1; off < 64; off <<= 1) m = fmaxf(m, __shfl_xor(m, off));
        float ptil = act ? __expf(sc - m) : 0.f;
        float s = ptil;
#pragma unroll
        for (int off = 1; off < 64; off <<= 1) s += __shfl_xor(s, off);
        float p = ptil * (1.f / (s + GAT_EPS));

        auto CONSUME = [&](unsigned short (&buf)[8], int base) {
#pragma unroll
            for (int u = 0; u < 8; u++) {
                float pj = rdlanef(p, base + u);
                f32x2 f = __builtin_amdgcn_cvt_pk_f32_fp8((int)buf[u], false);
                a0 += pj * f.x; a1 += pj * f.y;
            }
        };
        CONSUME(wA, 0);
        if (cnt > 8)  { if (cnt > 32) ISSUE(wA, 32); CONSUME(wB, 8); }
        if (cnt > 16) { if (cnt > 40) ISSUE(wB, 40); CONSUME(wC, 16); }
        if (cnt > 24) { if (cnt > 48) ISSUE(wC, 48); CONSUME(wD, 24); }
        if (cnt > 32) { if (cnt > 56) ISSUE(wD, 56); CONSUME(wA, 32); }
        if (cnt > 40) CONSUME(wB, 40);
        if (cnt > 48) CONSUME(wC, 48);
        if (cnt > 56) CONSUME(wD, 56);
    } else {
        float m = -1e30f, s = 0.f;
        int sidx = 0; float ssc = -1e30f;
        for (int e0 = start; e0 < end; e0 += 64) {
            int e = e0 + lane;
            bool act = e < end;
            int idx = act ? esrc[e] : 0;
            float sc = -1e30f;
            if (act) {
                sc = ss[idx] + sd;
                sc = sc > 0.f ? sc : ALPHA * sc;
            }
            sidx = idx; ssc = sc;
            float mn = fmaxf(m, sc);
            s = s * __expf(m - mn) + (act ? __expf(sc - mn) : 0.f);
            m = mn;
        }
        float lm = m;
#pragma unroll
        for (int off = 1; off < 64; off <<= 1) m = fmaxf(m, __shfl_xor(m, off));
        float ptil = s * __expf(lm - m);
        s = ptil;
#pragma unroll
        for (int off = 1; off < 64; off <<= 1) s += __shfl_xor(s, off);
        float inv = 1.f / (s + GAT_EPS);

        int lastStart = start + (((end - start - 1) >> 6) << 6);
        for (int e0 = start; e0 < end; e0 += 64) {
            int e = e0 + lane;
            bool act = e < end;
            int idx; float p;
            if (e0 == lastStart) {
                idx = sidx;
                p = act ? __expf(ssc - m) * inv : 0.f;
            } else {
                idx = act ? esrc[e] : 0;
                float sc = -1e30f;
                if (act) {
                    sc = ss[idx] + sd;
                    sc = sc > 0.f ? sc : ALPHA * sc;
                }
                p = act ? __expf(sc - m) * inv : 0.f;
            }
            int cn = end - e0; if (cn > 64) cn = 64;
            int j = 0;
            for (; j + 4 <= cn; j += 4) {
                int i0 = __builtin_amdgcn_readlane(idx, j);
                int i1 = __builtin_amdgcn_readlane(idx, j + 1);
                int i2 = __builtin_amdgcn_readlane(idx, j + 2);
                int i3 = __builtin_amdgcn_readlane(idx, j + 3);
                float p0 = rdlanef(p, j), p1 = rdlanef(p, j + 1);
                float p2 = rdlanef(p, j + 2), p3 = rdlanef(p, j + 3);
                unsigned short w0 = *(const unsigned short*)(Wb + (size_t)i0 * 768);
                unsigned short w1 = *(const unsigned short*)(Wb + (size_t)i1 * 768);
                unsigned short w2 = *(const unsigned short*)(Wb + (size_t)i2 * 768);
                unsigned short w3 = *(const unsigned short*)(Wb + (size_t)i3 * 768);
                f32x2 f0 = __builtin_amdgcn_cvt_pk_f32_fp8((int)w0, false);
                f32x2 f1 = __builtin_amdgcn_cvt_pk_f32_fp8((int)w1, false);
                f32x2 f2 = __builtin_amdgcn_cvt_pk_f32_fp8((int)w2, false);
                f32x2 f3 = __builtin_amdgcn_cvt_pk_f32_fp8((int)w3, false);
                a0 += p0 * f0.x + p1 * f1.x + p2 * f2.x + p3 * f3.x;
                a1 += p0 * f0.y + p1 * f1.y + p2 * f2.y + p3 * f3.y;
            }
            for (; j < cn; j++) {
                int ij = __builtin_amdgcn_readlane(idx, j);
                float pj = rdlanef(p, j);
                unsigned short w = *(const unsigned short*)(Wb + (size_t)ij * 768);
                f32x2 f = __builtin_amdgcn_cvt_pk_f32_fp8((int)w, false);
                a0 += pj * f.x; a1 += pj * f.y;
            }
        }
    }

    if (lane < 62) {
        part[h][2 * lane]     = a0;
        part[h][2 * lane + 1] = a1;
    }
    __syncthreads();
    if (t < 121) {
        float tot = (part[0][t] + part[1][t] + part[2][t] +
                     part[3][t] + part[4][t] + part[5][t]) * (1.f / 6.f);
        out[(size_t)n * 121 + t] = 1.f / (1.f + __expf(-tot));
    }
}

extern "C" void kernel_launch(void* const* d_in, const int* in_sizes, int n_in,
                              void* d_out, int out_size, void* d_ws, size_t ws_size,
                              hipStream_t stream) {
    const float* x  = (const float*)d_in[0];
    const int*   ei = (const int*)d_in[1];
    const float* W1 = (const float*)d_in[2];
    const float* a1 = (const float*)d_in[3];
    const float* W2 = (const float*)d_in[4];
    const float* a2 = (const float*)d_in[5];
    const float* W3 = (const float*)d_in[6];
    const float* a3 = (const float*)d_in[7];
    float* out = (float*)d_out;
    const int N = N_NODES, E = N_EDGES;
    const int* src = ei;
    const int* dst = ei + E;

    char* ws = (char*)d_ws;
    size_t off = 0;
    auto alloc = [&](size_t b) { size_t o = off; off += (b + 255) & ~(size_t)255; return o; };
    _Float16* X16  = (_Float16*)(ws + alloc((size_t)MPAD * 1024 * 2));  // x1 then x2 (fp16)
    unsigned char* WH8 = (unsigned char*)(ws + alloc((size_t)MPAD * 1024)); // per-layer Wh (fp8)
    _Float16* BT16 = (_Float16*)(ws + alloc((size_t)BT_ROWS * 1024 * 2));
    _Float16* A1   = (_Float16*)(ws + alloc((size_t)MPAD * 64 * 2));
    _Float16* BT1  = (_Float16*)(ws + alloc((size_t)BT_ROWS * 64 * 2));
    float* SPRE   = (float*)(ws + alloc((size_t)12 * N * 4));
    int*   rowptr = (int*)(ws + alloc((size_t)(N + 1) * 4));
    int*   cursor = (int*)(ws + alloc((size_t)N * 4));
    int*   counts = (int*)(ws + alloc((size_t)N * 4));
    int*   excl   = (int*)(ws + alloc((size_t)N * 4));
    int*   partial= (int*)(ws + alloc((size_t)SCAN_BLKS * 4));
    int*   esrc   = (int*)(ws + alloc((size_t)E * 4));

    // CSR by dst
    hipMemsetAsync(counts, 0, (size_t)N * 4, stream);
    hist_kernel<<<(E + 255) / 256, 256, 0, stream>>>(dst, counts, E);
    scan1_kernel<<<SCAN_BLKS, 256, 0, stream>>>(counts, excl, partial, N);
    scan2_kernel<<<1, 128, 0, stream>>>(partial);
    scan3_kernel<<<SCAN_BLKS, 256, 0, stream>>>(excl, partial, rowptr, cursor, N, E);
    scatter_kernel<<<(E + 255) / 256, 256, 0, stream>>>(src, dst, cursor, esrc, E);
    hipMemsetAsync(X16 + (size_t)N * 1024, 0, (size_t)(MPAD - N) * 1024 * 2, stream);

    // ---- layer 1: 50 -> 4x256 concat ----
    pack_x16<<<MPAD * 64 / 256, 256, 0, stream>>>(x, A1);
    pack_bt1<<<1024 * 64 / 256, 256, 0, stream>>>(W1, BT1);
    wtilde_kernel<<<dim3(64, 8), 64, 0, stream>>>(W1, a1, BT1, 50, 64, 256, 4, 1024);
    gemm_f16<<<8 * RHI * 9, 256, 0, stream>>>(A1, BT1, WH8, SPRE, N, 1024, 1024, 64, 9);
    attagg256_kernel<<<N, 256, 0, stream>>>(rowptr, esrc, SPRE, WH8, X16, 0, N);

    // ---- layer 2: 1024 -> 4x256 concat + skip ----
    pack_bt16<<<dim3(4, 1024), 256, 0, stream>>>(W2, BT16, 256, 256, 1024);
    wtilde_kernel<<<dim3(1024, 8), 64, 0, stream>>>(W2, a2, BT16, 1024, 1024, 256, 4, 1024);
    gemm_f16<<<8 * RHI * 9, 256, 0, stream>>>(X16, BT16, WH8, SPRE, N, 1024, 1024, 1024, 9);
    attagg256_kernel<<<N, 256, 0, stream>>>(rowptr, esrc, SPRE, WH8, X16, 1, N);

    // ---- layer 3: 1024 -> 6x121 (stride 124, zero-padded), mean + sigmoid ----
    pack_bt16<<<dim3(4, 744), 256, 0, stream>>>(W3, BT16, 121, 124, 744);
    wtilde_kernel<<<dim3(1024, 12), 64, 0, stream>>>(W3, a3, BT16, 1024, 1024, 121, 6, 744);
    gemm_f16<<<8 * RHI * 6, 256, 0, stream>>>(X16, BT16, WH8, SPRE, N, 744, 768, 1024, 6);
    attagg726_kernel<<<N, 384, 0, stream>>>(rowptr, esrc, SPRE, WH8, out, N);
}

// Round 7
// 434.172 us; speedup vs baseline: 1.0707x; 1.0239x over previous
//
#include <hip/hip_runtime.h>
#include <cstdint>

#define N_NODES 20000
#define N_EDGES 320000
#define ALPHA 0.2f
#define GAT_EPS 1e-16f
#define MPAD 20096           // 157 * 128
#define RBLK 157
#define RHI 20               // ceil(157/8)
#define SCAN_BLKS 80
#define BT_ROWS 1152         // 9 col-blocks * 128

typedef __attribute__((ext_vector_type(8))) _Float16 half8;
typedef __attribute__((ext_vector_type(4))) _Float16 half4t;
typedef __attribute__((ext_vector_type(16))) float f32x16;
typedef __attribute__((ext_vector_type(2))) float f32x2;

__device__ __forceinline__ float elu1(float x) { return x > 0.f ? x : __expf(x) - 1.f; }

__device__ __forceinline__ unsigned char f2fp8(float x) {
    return (unsigned char)(__builtin_amdgcn_cvt_pk_fp8_f32(x, 0.f, 0, false) & 0xff);
}

__device__ __forceinline__ void async16(const void* g, void* l) {
    __builtin_amdgcn_global_load_lds(
        (const __attribute__((address_space(1))) unsigned int*)g,
        (__attribute__((address_space(3))) unsigned int*)l, 16, 0, 0);
}

__device__ __forceinline__ float rdlanef(float v, int j) {
    return __int_as_float(__builtin_amdgcn_readlane(__float_as_int(v), j));
}

// ---------------- CSR build ----------------
__global__ void hist_kernel(const int* __restrict__ dst, int* __restrict__ counts, int E) {
    int e = blockIdx.x * blockDim.x + threadIdx.x;
    if (e < E) atomicAdd(&counts[dst[e]], 1);
}

__global__ void scan1_kernel(const int* __restrict__ counts, int* __restrict__ excl,
                             int* __restrict__ partial, int N) {
    __shared__ int sh[256];
    int t = threadIdx.x, b = blockIdx.x;
    int i = b * 256 + t;
    int v = (i < N) ? counts[i] : 0;
    sh[t] = v;
    __syncthreads();
    for (int d = 1; d < 256; d <<= 1) {
        int x = (t >= d) ? sh[t - d] : 0;
        __syncthreads();
        sh[t] += x;
        __syncthreads();
    }
    if (i < N) excl[i] = sh[t] - v;
    if (t == 255) partial[b] = sh[255];
}

__global__ void scan2_kernel(int* __restrict__ partial) {
    __shared__ int sh[128];
    int t = threadIdx.x;
    int v = (t < SCAN_BLKS) ? partial[t] : 0;
    sh[t] = v;
    __syncthreads();
    for (int d = 1; d < 128; d <<= 1) {
        int x = (t >= d) ? sh[t - d] : 0;
        __syncthreads();
        sh[t] += x;
        __syncthreads();
    }
    if (t < SCAN_BLKS) partial[t] = sh[t] - v;
}

__global__ void scan3_kernel(const int* __restrict__ excl, const int* __restrict__ partial,
                             int* __restrict__ rowptr, int* __restrict__ cursor, int N, int E) {
    int t = threadIdx.x, b = blockIdx.x;
    int i = b * 256 + t;
    if (i < N) {
        int v = excl[i] + partial[b];
        rowptr[i] = v;
        cursor[i] = v;
    }
    if (i == 0) rowptr[N] = E;
}

__global__ void scatter_kernel(const int* __restrict__ src, const int* __restrict__ dst,
                               int* __restrict__ cursor, int* __restrict__ esrc, int E) {
    int e = blockIdx.x * blockDim.x + threadIdx.x;
    if (e < E) {
        int p = atomicAdd(&cursor[dst[e]], 1);
        esrc[p] = src[e];
    }
}

// ---------------- packs ----------------
__global__ void pack_x16(const float* __restrict__ x, _Float16* __restrict__ A) {
    int idx = blockIdx.x * 256 + threadIdx.x;   // MPAD*64
    int r = idx >> 6, c = idx & 63;
    float v = (r < N_NODES && c < 50) ? x[r * 50 + c] : 0.f;
    A[idx] = (_Float16)v;
}

__global__ void pack_bt1(const float* __restrict__ W, _Float16* __restrict__ Bt) {
    int idx = blockIdx.x * 256 + threadIdx.x;   // 1024*64
    int c = idx >> 6, k = idx & 63;
    int h = c >> 8, f = c & 255;
    float v = (k < 50) ? W[((size_t)h * 50 + k) * 256 + f] : 0.f;
    Bt[idx] = (_Float16)v;
}

// generic: BT row c -> head h=c/Fpad, col f=c%Fpad; zero for f>=F (alignment pad)
__global__ void pack_bt16(const float* __restrict__ W, _Float16* __restrict__ Bt,
                          int F, int Fpad, int Ctot) {
    int c = blockIdx.y;
    int k = blockIdx.x * blockDim.x + threadIdx.x;
    float v = 0.f;
    if (c < Ctot) {
        int h = c / Fpad, f = c - h * Fpad;
        if (f < F) v = W[(size_t)h * 1024 * F + (size_t)k * F + f];
    }
    Bt[(size_t)c * 1024 + k] = (_Float16)v;
}

// W~ cols appended at BT rows [Nfeat, Nfeat+2H); gridDim.y MUST be 2*H.
__global__ __launch_bounds__(64) void wtilde_kernel(const float* __restrict__ W,
                                                    const float* __restrict__ a,
                                                    _Float16* __restrict__ BT, int Kreal,
                                                    int Kdim, int F, int H, int Nfeat) {
    int k = blockIdx.x, j = blockIdx.y;
    if (j >= 2 * H) return;
    int lane = threadIdx.x;
    int h = j < H ? j : j - H;
    int ao = j < H ? 0 : F;
    float s = 0.f;
    if (k < Kreal) {
        const float* wp = W + ((size_t)h * Kreal + k) * F;
        const float* ap = a + (size_t)h * 2 * F + ao;
        for (int f = lane; f < F; f += 64) s += wp[f] * ap[f];
    }
#pragma unroll
    for (int off = 32; off; off >>= 1) s += __shfl_down(s, off);
    if (lane == 0) BT[(size_t)(Nfeat + j) * Kdim + k] = (_Float16)s;
}

// ---------------- fp16 MFMA GEMM (32x32x16) ----------------
// Single-buffer 2-barrier structure (measured 64.9us / MfmaUtil 31% at K=1024).
// mode 0: C8 = fp8(acc) for gc<Nfeat, SPRE cols for gc in [Nfeat, Nfeat+12).
// mode 1: block-diagonal layer-1 output: per col-block cb, A-slice cols
//         [(cb>>1)*64, +64) (head cb>>1's xbar), epilogue writes fp16 elu(elu(acc)).
__global__ __launch_bounds__(256) void gemm_f16(const _Float16* __restrict__ A,
                                                const _Float16* __restrict__ BT,
                                                unsigned char* __restrict__ C8,
                                                float* __restrict__ SPRE,
                                                int M, int Nfeat, int ld, int Kdim, int Cblk,
                                                int ldA, int mode) {
    int id = blockIdx.x;
    int xm = id & 7, q = id >> 3;
    int cb = q % Cblk, rh = q / Cblk;
    int rb = rh * 8 + xm;
    if (rb >= RBLK) return;
    __shared__ __align__(16) _Float16 sA[128 * 64];
    __shared__ __align__(16) _Float16 sB[128 * 64];
    int t = threadIdx.x;
    int row0 = rb * 128, col0 = cb * 128;
    int lane = t & 63, wave = t >> 6;
    int wm = wave >> 1, wn = wave & 1;
    int l31 = lane & 31;
    int lhi = lane >> 5;

    int koff = (mode == 1) ? ((cb >> 1) * 64) : 0;
    const _Float16* gA = A + (size_t)row0 * ldA + koff;
    const _Float16* gB = BT + (size_t)col0 * Kdim;

    int sR[4], sgl[4];
#pragma unroll
    for (int i = 0; i < 4; i++) {
        int m = i * 256 + t;
        sR[i] = m >> 3;
        sgl[i] = (m & 7) ^ (sR[i] & 7);
    }

    f32x16 acc[2][2] = {};

    for (int k0 = 0; k0 < Kdim; k0 += 64) {
        __syncthreads();
#pragma unroll
        for (int i = 0; i < 4; i++) {
            const _Float16* pa = gA + (size_t)sR[i] * ldA + k0 + sgl[i] * 8;
            const _Float16* pb = gB + (size_t)sR[i] * Kdim + k0 + sgl[i] * 8;
            async16(pa, sA + (i * 256 + t) * 8);
            async16(pb, sB + (i * 256 + t) * 8);
        }
        __syncthreads();
#pragma unroll
        for (int kk = 0; kk < 4; kk++) {
            int g = kk * 2 + lhi;
            half8 af[2], bf[2];
#pragma unroll
            for (int mt = 0; mt < 2; mt++) {
                int R = wm * 64 + mt * 32 + l31;
                int gp = g ^ (R & 7);
                af[mt] = *(const half8*)(sA + R * 64 + gp * 8);
            }
#pragma unroll
            for (int nt = 0; nt < 2; nt++) {
                int R = wn * 64 + nt * 32 + l31;
                int gp = g ^ (R & 7);
                bf[nt] = *(const half8*)(sB + R * 64 + gp * 8);
            }
#pragma unroll
            for (int mt = 0; mt < 2; mt++)
#pragma unroll
                for (int nt = 0; nt < 2; nt++)
                    acc[mt][nt] = __builtin_amdgcn_mfma_f32_32x32x16_f16(af[mt], bf[nt], acc[mt][nt], 0, 0, 0);
        }
    }

    int cb32 = col0 + wn * 64 + l31;
    int rb32 = row0 + wm * 64 + 4 * lhi;
    if (mode == 1) {
        _Float16* C16 = (_Float16*)C8;
#pragma unroll
        for (int mt = 0; mt < 2; mt++)
#pragma unroll
            for (int nt = 0; nt < 2; nt++) {
                int gc = cb32 + nt * 32;
                if (gc < Nfeat) {
#pragma unroll
                    for (int r = 0; r < 16; r++) {
                        int gr = rb32 + mt * 32 + (r & 3) + 8 * (r >> 2);
                        if (gr < M) C16[(size_t)gr * ld + gc] = (_Float16)elu1(elu1(acc[mt][nt][r]));
                    }
                }
            }
        return;
    }
#pragma unroll
    for (int mt = 0; mt < 2; mt++)
#pragma unroll
        for (int nt = 0; nt < 2; nt++) {
            int gc = cb32 + nt * 32;
            if (gc < Nfeat) {
#pragma unroll
                for (int r = 0; r < 16; r++) {
                    int gr = rb32 + mt * 32 + (r & 3) + 8 * (r >> 2);
                    if (gr < M) C8[(size_t)gr * ld + gc] = f2fp8(acc[mt][nt][r]);
                }
            } else if (gc < Nfeat + 12) {
                int j = gc - Nfeat;
#pragma unroll
                for (int r = 0; r < 16; r++) {
                    int gr = rb32 + mt * 32 + (r & 3) + 8 * (r >> 2);
                    if (gr < M) SPRE[(size_t)j * N_NODES + gr] = acc[mt][nt][r];
                }
            }
        }
}

// ---------------- layer 1: attention + x-aggregation (gather x, not Wh) ----------------
// Aggregation is linear: sum_e p_e*(x W) = (sum_e p_e*x) W. Gather the 128B fp16 x-rows
// (table 2.6MB -> L2-RESIDENT per XCD, vs 20MB Wh) and matmul afterwards. Block = node,
// wave = head; lane covers one of 64 fp16 cols (50 real + zero pad). Same 4-deep
// issue-before-reduce pipeline as attagg256. Output xbar -> XB[n][h*64+lane].
__global__ __launch_bounds__(256) void aggx1_kernel(const int* __restrict__ rowptr,
                                                    const int* __restrict__ esrc,
                                                    const float* __restrict__ SPRE,
                                                    const _Float16* __restrict__ A1,
                                                    _Float16* __restrict__ XB, int N) {
    int n = blockIdx.x;
    int h = threadIdx.x >> 6;
    int lane = threadIdx.x & 63;
    int start = rowptr[n], end = rowptr[n + 1];
    int cnt = end - start;
    const float* ss = SPRE + (size_t)h * N;
    float sd = SPRE[(size_t)(4 + h) * N + n];
    const unsigned char* Wb = (const unsigned char*)A1 + 2 * lane;
    float acc = 0.f;

    if (cnt <= 64) {
        int e = start + lane;
        bool act = e < end;
        int idx = act ? esrc[e] : 0;
        int voff = idx << 7;             // byte offset of 128B row

        unsigned short wA[8], wB[8], wC[8], wD[8];
        auto ISSUE = [&](unsigned short (&buf)[8], int base) {
#pragma unroll
            for (int u = 0; u < 8; u++) {
                int off = __builtin_amdgcn_readlane(voff, base + u);
                buf[u] = *(const unsigned short*)(Wb + (unsigned)off);
            }
        };
        ISSUE(wA, 0);
        if (cnt > 8)  ISSUE(wB, 8);
        if (cnt > 16) ISSUE(wC, 16);
        if (cnt > 24) ISSUE(wD, 24);

        float sc = -1e30f;
        if (act) {
            sc = ss[idx] + sd;
            sc = sc > 0.f ? sc : ALPHA * sc;
        }
        float m = sc;
#pragma unroll
        for (int off = 1; off < 64; off <<= 1) m = fmaxf(m, __shfl_xor(m, off));
        float ptil = act ? __expf(sc - m) : 0.f;
        float s = ptil;
#pragma unroll
        for (int off = 1; off < 64; off <<= 1) s += __shfl_xor(s, off);
        float p = ptil * (1.f / (s + GAT_EPS));

        auto CONSUME = [&](unsigned short (&buf)[8], int base) {
#pragma unroll
            for (int u = 0; u < 8; u++) {
                float pj = rdlanef(p, base + u);
                acc += pj * (float)(*(const _Float16*)&buf[u]);
            }
        };
        CONSUME(wA, 0);
        if (cnt > 8)  { if (cnt > 32) ISSUE(wA, 32); CONSUME(wB, 8); }
        if (cnt > 16) { if (cnt > 40) ISSUE(wB, 40); CONSUME(wC, 16); }
        if (cnt > 24) { if (cnt > 48) ISSUE(wC, 48); CONSUME(wD, 24); }
        if (cnt > 32) { if (cnt > 56) ISSUE(wD, 56); CONSUME(wA, 32); }
        if (cnt > 40) CONSUME(wB, 40);
        if (cnt > 48) CONSUME(wC, 48);
        if (cnt > 56) CONSUME(wD, 56);
    } else {
        // fallback: chunked (deg > 64)
        float m = -1e30f, s = 0.f;
        int sidx = 0; float ssc = -1e30f;
        for (int e0 = start; e0 < end; e0 += 64) {
            int e = e0 + lane;
            bool act = e < end;
            int idx = act ? esrc[e] : 0;
            float sc = -1e30f;
            if (act) {
                sc = ss[idx] + sd;
                sc = sc > 0.f ? sc : ALPHA * sc;
            }
            sidx = idx; ssc = sc;
            float mn = fmaxf(m, sc);
            s = s * __expf(m - mn) + (act ? __expf(sc - mn) : 0.f);
            m = mn;
        }
        float lm = m;
#pragma unroll
        for (int off = 1; off < 64; off <<= 1) m = fmaxf(m, __shfl_xor(m, off));
        float ptil = s * __expf(lm - m);
        s = ptil;
#pragma unroll
        for (int off = 1; off < 64; off <<= 1) s += __shfl_xor(s, off);
        float inv = 1.f / (s + GAT_EPS);

        int lastStart = start + (((end - start - 1) >> 6) << 6);
        for (int e0 = start; e0 < end; e0 += 64) {
            int e = e0 + lane;
            bool act = e < end;
            int idx; float p;
            if (e0 == lastStart) {
                idx = sidx;
                p = act ? __expf(ssc - m) * inv : 0.f;
            } else {
                idx = act ? esrc[e] : 0;
                float sc = -1e30f;
                if (act) {
                    sc = ss[idx] + sd;
                    sc = sc > 0.f ? sc : ALPHA * sc;
                }
                p = act ? __expf(sc - m) * inv : 0.f;
            }
            int cn = end - e0; if (cn > 64) cn = 64;
            for (int j = 0; j < cn; j++) {
                int ij = __builtin_amdgcn_readlane(idx, j);
                float pj = rdlanef(p, j);
                unsigned short w = *(const unsigned short*)(Wb + ((size_t)(unsigned)ij << 7));
                acc += pj * (float)(*(const _Float16*)&w);
            }
        }
    }

    XB[(size_t)n * 256 + h * 64 + lane] = (_Float16)acc;
}

// ---------------- fused attention + aggregation, Fout=256 (layer 2) ----------------
__global__ __launch_bounds__(256) void attagg256_kernel(const int* __restrict__ rowptr,
                                                        const int* __restrict__ esrc,
                                                        const float* __restrict__ SPRE,
                                                        const unsigned char* __restrict__ WH8,
                                                        _Float16* __restrict__ X16,
                                                        int use_skip, int N) {
    int n = blockIdx.x;
    int h = threadIdx.x >> 6;
    int lane = threadIdx.x & 63;
    int start = rowptr[n], end = rowptr[n + 1];
    int cnt = end - start;
    const float* ss = SPRE + (size_t)h * N;
    float sd = SPRE[(size_t)(4 + h) * N + n];
    const unsigned char* Wb = WH8 + h * 256 + lane * 4;
    float a0 = 0.f, a1 = 0.f, a2 = 0.f, a3 = 0.f;

    if (cnt <= 64) {
        int e = start + lane;
        bool act = e < end;
        int idx = act ? esrc[e] : 0;

        unsigned int wA[8], wB[8], wC[8], wD[8];
        auto ISSUE = [&](unsigned int (&buf)[8], int base) {
#pragma unroll
            for (int u = 0; u < 8; u++) {
                int ij = __builtin_amdgcn_readlane(idx, base + u);
                buf[u] = *(const unsigned int*)(Wb + ((size_t)(unsigned)ij << 10));
            }
        };
        ISSUE(wA, 0);
        if (cnt > 8)  ISSUE(wB, 8);
        if (cnt > 16) ISSUE(wC, 16);
        if (cnt > 24) ISSUE(wD, 24);

        float sc = -1e30f;
        if (act) {
            sc = ss[idx] + sd;
            sc = sc > 0.f ? sc : ALPHA * sc;
        }
        float m = sc;
#pragma unroll
        for (int off = 1; off < 64; off <<= 1) m = fmaxf(m, __shfl_xor(m, off));
        float ptil = act ? __expf(sc - m) : 0.f;
        float s = ptil;
#pragma unroll
        for (int off = 1; off < 64; off <<= 1) s += __shfl_xor(s, off);
        float p = ptil * (1.f / (s + GAT_EPS));

        auto CONSUME = [&](unsigned int (&buf)[8], int base) {
#pragma unroll
            for (int u = 0; u < 8; u++) {
                float pj = rdlanef(p, base + u);
                f32x2 lo = __builtin_amdgcn_cvt_pk_f32_fp8((int)buf[u], false);
                f32x2 hi = __builtin_amdgcn_cvt_pk_f32_fp8((int)buf[u], true);
                a0 += pj * lo.x; a1 += pj * lo.y; a2 += pj * hi.x; a3 += pj * hi.y;
            }
        };
        CONSUME(wA, 0);
        if (cnt > 8)  { if (cnt > 32) ISSUE(wA, 32); CONSUME(wB, 8); }
        if (cnt > 16) { if (cnt > 40) ISSUE(wB, 40); CONSUME(wC, 16); }
        if (cnt > 24) { if (cnt > 48) ISSUE(wC, 48); CONSUME(wD, 24); }
        if (cnt > 32) { if (cnt > 56) ISSUE(wD, 56); CONSUME(wA, 32); }
        if (cnt > 40) CONSUME(wB, 40);
        if (cnt > 48) CONSUME(wC, 48);
        if (cnt > 56) CONSUME(wD, 56);
    } else {
        float m = -1e30f, s = 0.f;
        int sidx = 0; float ssc = -1e30f;
        for (int e0 = start; e0 < end; e0 += 64) {
            int e = e0 + lane;
            bool act = e < end;
            int idx = act ? esrc[e] : 0;
            float sc = -1e30f;
            if (act) {
                sc = ss[idx] + sd;
                sc = sc > 0.f ? sc : ALPHA * sc;
            }
            sidx = idx; ssc = sc;
            float mn = fmaxf(m, sc);
            s = s * __expf(m - mn) + (act ? __expf(sc - mn) : 0.f);
            m = mn;
        }
        float lm = m;
#pragma unroll
        for (int off = 1; off < 64; off <<= 1) m = fmaxf(m, __shfl_xor(m, off));
        float ptil = s * __expf(lm - m);
        s = ptil;
#pragma unroll
        for (int off = 1; off < 64; off <<= 1) s += __shfl_xor(s, off);
        float inv = 1.f / (s + GAT_EPS);

        int lastStart = start + (((end - start - 1) >> 6) << 6);
        for (int e0 = start; e0 < end; e0 += 64) {
            int e = e0 + lane;
            bool act = e < end;
            int idx; float p;
            if (e0 == lastStart) {
                idx = sidx;
                p = act ? __expf(ssc - m) * inv : 0.f;
            } else {
                idx = act ? esrc[e] : 0;
                float sc = -1e30f;
                if (act) {
                    sc = ss[idx] + sd;
                    sc = sc > 0.f ? sc : ALPHA * sc;
                }
                p = act ? __expf(sc - m) * inv : 0.f;
            }
            int cn = end - e0; if (cn > 64) cn = 64;
            for (int j = 0; j < cn; j++) {
                int ij = __builtin_amdgcn_readlane(idx, j);
                float pj = rdlanef(p, j);
                unsigned int w = *(const unsigned int*)(Wb + (size_t)ij * 1024);
                f32x2 lo = __builtin_amdgcn_cvt_pk_f32_fp8((int)w, false);
                f32x2 hi = __builtin_amdgcn_cvt_pk_f32_fp8((int)w, true);
                a0 += pj * lo.x; a1 += pj * lo.y; a2 += pj * hi.x; a3 += pj * hi.y;
            }
        }
    }

    size_t o = (size_t)n * 1024 + h * 256 + lane * 4;
    float v0, v1, v2, v3;
    if (use_skip) {
        half4t sk = *(const half4t*)(X16 + o);
        v0 = elu1(elu1(a0) + (float)sk.x);
        v1 = elu1(elu1(a1) + (float)sk.y);
        v2 = elu1(elu1(a2) + (float)sk.z);
        v3 = elu1(elu1(a3) + (float)sk.w);
    } else {
        v0 = elu1(elu1(a0)); v1 = elu1(elu1(a1));
        v2 = elu1(elu1(a2)); v3 = elu1(elu1(a3));
    }
    half4t r;
    r.x = (_Float16)v0; r.y = (_Float16)v1; r.z = (_Float16)v2; r.w = (_Float16)v3;
    *(half4t*)(X16 + o) = r;
}

// ---------------- fused attention + aggregation, layer 3 (6 heads, Fout=121) ----------
__global__ __launch_bounds__(384) void attagg726_kernel(const int* __restrict__ rowptr,
                                                        const int* __restrict__ esrc,
                                                        const float* __restrict__ SPRE,
                                                        const unsigned char* __restrict__ WH8,
                                                        float* __restrict__ out, int N) {
    __shared__ float part[6][124];
    int n = blockIdx.x;
    int t = threadIdx.x;
    int h = t >> 6;
    int lane = t & 63;
    int start = rowptr[n], end = rowptr[n + 1];
    int cnt = end - start;
    const float* ss = SPRE + (size_t)h * N;
    float sd = SPRE[(size_t)(6 + h) * N + n];
    const unsigned char* Wb = WH8 + h * 124 + 2 * lane;
    float a0 = 0.f, a1 = 0.f;

    if (cnt <= 64) {
        int e = start + lane;
        bool act = e < end;
        int idx = act ? esrc[e] : 0;

        unsigned short wA[8], wB[8], wC[8], wD[8];
        auto ISSUE = [&](unsigned short (&buf)[8], int base) {
#pragma unroll
            for (int u = 0; u < 8; u++) {
                int ij = __builtin_amdgcn_readlane(idx, base + u);
                buf[u] = *(const unsigned short*)(Wb + (size_t)(unsigned)ij * 768u);
            }
        };
        ISSUE(wA, 0);
        if (cnt > 8)  ISSUE(wB, 8);
        if (cnt > 16) ISSUE(wC, 16);
        if (cnt > 24) ISSUE(wD, 24);

        float sc = -1e30f;
        if (act) {
            sc = ss[idx] + sd;
            sc = sc > 0.f ? sc : ALPHA * sc;
        }
        float m = sc;
#pragma unroll
        for (int off = 1; off < 64; off <<= 1) m = fmaxf(m, __shfl_xor(m, off));
        float ptil = act ? __expf(sc - m) : 0.f;
        float s = ptil;
#pragma unroll
        for (int off = 1; off < 64; off <<= 1) s += __shfl_xor(s, off);
        float p = ptil * (1.f / (s + GAT_EPS));

        auto CONSUME = [&](unsigned short (&buf)[8], int base) {
#pragma unroll
            for (int u = 0; u < 8; u++) {
                float pj = rdlanef(p, base + u);
                f32x2 f = __builtin_amdgcn_cvt_pk_f32_fp8((int)buf[u], false);
                a0 += pj * f.x; a1 += pj * f.y;
            }
        };
        CONSUME(wA, 0);
        if (cnt > 8)  { if (cnt > 32) ISSUE(wA, 32); CONSUME(wB, 8); }
        if (cnt > 16) { if (cnt > 40) ISSUE(wB, 40); CONSUME(wC, 16); }
        if (cnt > 24) { if (cnt > 48) ISSUE(wC, 48); CONSUME(wD, 24); }
        if (cnt > 32) { if (cnt > 56) ISSUE(wD, 56); CONSUME(wA, 32); }
        if (cnt > 40) CONSUME(wB, 40);
        if (cnt > 48) CONSUME(wC, 48);
        if (cnt > 56) CONSUME(wD, 56);
    } else {
        float m = -1e30f, s = 0.f;
        int sidx = 0; float ssc = -1e30f;
        for (int e0 = start; e0 < end; e0 += 64) {
            int e = e0 + lane;
            bool act = e < end;
            int idx = act ? esrc[e] : 0;
            float sc = -1e30f;
            if (act) {
                sc = ss[idx] + sd;
                sc = sc > 0.f ? sc : ALPHA * sc;
            }
            sidx = idx; ssc = sc;
            float mn = fmaxf(m, sc);
            s = s * __expf(m - mn) + (act ? __expf(sc - mn) : 0.f);
            m = mn;
        }
        float lm = m;
#pragma unroll
        for (int off = 1; off < 64; off <<= 1) m = fmaxf(m, __shfl_xor(m, off));
        float ptil = s * __expf(lm - m);
        s = ptil;
#pragma unroll
        for (int off = 1; off < 64; off <<= 1) s += __shfl_xor(s, off);
        float inv = 1.f / (s + GAT_EPS);

        int lastStart = start + (((end - start - 1) >> 6) << 6);
        for (int e0 = start; e0 < end; e0 += 64) {
            int e = e0 + lane;
            bool act = e < end;
            int idx; float p;
            if (e0 == lastStart) {
                idx = sidx;
                p = act ? __expf(ssc - m) * inv : 0.f;
            } else {
                idx = act ? esrc[e] : 0;
                float sc = -1e30f;
                if (act) {
                    sc = ss[idx] + sd;
                    sc = sc > 0.f ? sc : ALPHA * sc;
                }
                p = act ? __expf(sc - m) * inv : 0.f;
            }
            int cn = end - e0; if (cn > 64) cn = 64;
            for (int j = 0; j < cn; j++) {
                int ij = __builtin_amdgcn_readlane(idx, j);
                float pj = rdlanef(p, j);
                unsigned short w = *(const unsigned short*)(Wb + (size_t)ij * 768);
                f32x2 f = __builtin_amdgcn_cvt_pk_f32_fp8((int)w, false);
                a0 += pj * f.x; a1 += pj * f.y;
            }
        }
    }

    if (lane < 62) {
        part[h][2 * lane]     = a0;
        part[h][2 * lane + 1] = a1;
    }
    __syncthreads();
    if (t < 121) {
        float tot = (part[0][t] + part[1][t] + part[2][t] +
                     part[3][t] + part[4][t] + part[5][t]) * (1.f / 6.f);
        out[(size_t)n * 121 + t] = 1.f / (1.f + __expf(-tot));
    }
}

extern "C" void kernel_launch(void* const* d_in, const int* in_sizes, int n_in,
                              void* d_out, int out_size, void* d_ws, size_t ws_size,
                              hipStream_t stream) {
    const float* x  = (const float*)d_in[0];
    const int*   ei = (const int*)d_in[1];
    const float* W1 = (const float*)d_in[2];
    const float* a1 = (const float*)d_in[3];
    const float* W2 = (const float*)d_in[4];
    const float* a2 = (const float*)d_in[5];
    const float* W3 = (const float*)d_in[6];
    const float* a3 = (const float*)d_in[7];
    float* out = (float*)d_out;
    const int N = N_NODES, E = N_EDGES;
    const int* src = ei;
    const int* dst = ei + E;

    char* ws = (char*)d_ws;
    size_t off = 0;
    auto alloc = [&](size_t b) { size_t o = off; off += (b + 255) & ~(size_t)255; return o; };
    _Float16* X16  = (_Float16*)(ws + alloc((size_t)MPAD * 1024 * 2));  // x1 then x2 (fp16)
    unsigned char* WH8 = (unsigned char*)(ws + alloc((size_t)MPAD * 1024)); // per-layer Wh (fp8)
    _Float16* BT16 = (_Float16*)(ws + alloc((size_t)BT_ROWS * 1024 * 2));
    _Float16* A1   = (_Float16*)(ws + alloc((size_t)MPAD * 64 * 2));
    _Float16* BT1  = (_Float16*)(ws + alloc((size_t)BT_ROWS * 64 * 2));
    _Float16* XB   = (_Float16*)(ws + alloc((size_t)MPAD * 256 * 2));  // layer-1 xbar (4 heads x 64)
    _Float16* BTS  = (_Float16*)(ws + alloc((size_t)128 * 64 * 2));    // layer-1 score cols
    float* SPRE   = (float*)(ws + alloc((size_t)12 * N * 4));
    int*   rowptr = (int*)(ws + alloc((size_t)(N + 1) * 4));
    int*   cursor = (int*)(ws + alloc((size_t)N * 4));
    int*   counts = (int*)(ws + alloc((size_t)N * 4));
    int*   excl   = (int*)(ws + alloc((size_t)N * 4));
    int*   partial= (int*)(ws + alloc((size_t)SCAN_BLKS * 4));
    int*   esrc   = (int*)(ws + alloc((size_t)E * 4));

    // CSR by dst
    hipMemsetAsync(counts, 0, (size_t)N * 4, stream);
    hist_kernel<<<(E + 255) / 256, 256, 0, stream>>>(dst, counts, E);
    scan1_kernel<<<SCAN_BLKS, 256, 0, stream>>>(counts, excl, partial, N);
    scan2_kernel<<<1, 128, 0, stream>>>(partial);
    scan3_kernel<<<SCAN_BLKS, 256, 0, stream>>>(excl, partial, rowptr, cursor, N, E);
    scatter_kernel<<<(E + 255) / 256, 256, 0, stream>>>(src, dst, cursor, esrc, E);
    hipMemsetAsync(X16 + (size_t)N * 1024, 0, (size_t)(MPAD - N) * 1024 * 2, stream);
    hipMemsetAsync(XB + (size_t)N * 256, 0, (size_t)(MPAD - N) * 256 * 2, stream);

    // ---- layer 1: scores from x@Wtil; aggregate x (L2-resident); block-diag GEMM ----
    pack_x16<<<MPAD * 64 / 256, 256, 0, stream>>>(x, A1);
    pack_bt1<<<1024 * 64 / 256, 256, 0, stream>>>(W1, BT1);
    wtilde_kernel<<<dim3(64, 8), 64, 0, stream>>>(W1, a1, BTS, 50, 64, 256, 4, 0);
    // scores only: Nfeat=0, Cblk=1 -> SPRE cols 0..7 (8..11 garbage, unused)
    gemm_f16<<<8 * RHI * 1, 256, 0, stream>>>(A1, BTS, WH8, SPRE, N, 0, 1024, 64, 1, 64, 0);
    aggx1_kernel<<<N, 256, 0, stream>>>(rowptr, esrc, SPRE, A1, XB, N);
    // xbar @ block-diag(W1) with elu(elu(.)) epilogue -> X16 fp16
    gemm_f16<<<8 * RHI * 8, 256, 0, stream>>>(XB, BT1, (unsigned char*)X16, SPRE, N, 1024, 1024, 64, 8, 256, 1);

    // ---- layer 2: 1024 -> 4x256 concat + skip ----
    pack_bt16<<<dim3(4, 1024), 256, 0, stream>>>(W2, BT16, 256, 256, 1024);
    wtilde_kernel<<<dim3(1024, 8), 64, 0, stream>>>(W2, a2, BT16, 1024, 1024, 256, 4, 1024);
    gemm_f16<<<8 * RHI * 9, 256, 0, stream>>>(X16, BT16, WH8, SPRE, N, 1024, 1024, 1024, 9, 1024, 0);
    attagg256_kernel<<<N, 256, 0, stream>>>(rowptr, esrc, SPRE, WH8, X16, 1, N);

    // ---- layer 3: 1024 -> 6x121 (stride 124, zero-padded), mean + sigmoid ----
    pack_bt16<<<dim3(4, 744), 256, 0, stream>>>(W3, BT16, 121, 124, 744);
    wtilde_kernel<<<dim3(1024, 12), 64, 0, stream>>>(W3, a3, BT16, 1024, 1024, 121, 6, 744);
    gemm_f16<<<8 * RHI * 6, 256, 0, stream>>>(X16, BT16, WH8, SPRE, N, 744, 768, 1024, 6, 1024, 0);
    attagg726_kernel<<<N, 384, 0, stream>>>(rowptr, esrc, SPRE, WH8, out, N);
}